// Round 3
// baseline (2647.109 us; speedup 1.0000x reference)
//
#include <hip/hip_runtime.h>
#include <hip/hip_bf16.h>
#include <stdint.h>

#define E_ 8
#define L_ 12
#define D_ 768
#define H_ 12
#define S_ 512
#define B_ 32
#define BS_ (B_*S_)   // 16384

typedef __attribute__((ext_vector_type(4))) float floatx4;
typedef __attribute__((ext_vector_type(8))) __bf16 bf16x8;
typedef __attribute__((ext_vector_type(4))) __bf16 bf16x4;

__device__ __forceinline__ __bf16 f2bf(float f) {
  unsigned u = __builtin_bit_cast(unsigned, f);
  u += 0x7fffu + ((u >> 16) & 1u);           // RNE
  unsigned short h = (unsigned short)(u >> 16);
  return __builtin_bit_cast(__bf16, h);
}

__device__ __forceinline__ float fexp2(float x) {
#if __has_builtin(__builtin_amdgcn_exp2f)
  return __builtin_amdgcn_exp2f(x);
#else
  return exp2f(x);
#endif
}

__device__ __forceinline__ void async16(const void* g, void* l) {
  __builtin_amdgcn_global_load_lds((__attribute__((address_space(1))) void*)g,
                                   (__attribute__((address_space(3))) void*)l,
                                   16, 0, 0);
}

// ---------------- routing stage 1: 64 blocks x 8 rows, coalesced partial sums ----------------
__global__ void routing_pool_kernel(const float* __restrict__ hidden,
                                    float* __restrict__ partial) {
  const int blk = blockIdx.x;    // 0..63
  const int tid = threadIdx.x;
  const float* base = hidden + (size_t)(B_-1)*S_*D_ + (size_t)blk*8*D_;
  float acc[3] = {0.f, 0.f, 0.f};
  for (int s = 0; s < 8; ++s) {
#pragma unroll
    for (int i = 0; i < 3; ++i)
      acc[i] += base[(size_t)s*D_ + tid + i*256];
  }
#pragma unroll
  for (int i = 0; i < 3; ++i) partial[(size_t)blk*D_ + tid + i*256] = acc[i];
}

// ---------------- routing stage 2: reduce partials, logits, argmax ----------------
__global__ void routing_finish_kernel(const float* __restrict__ partial,
                                      const float* __restrict__ rw,
                                      int* __restrict__ e_out) {
  __shared__ float pooled[D_];
  __shared__ float logits[E_];
  int tid = threadIdx.x;
#pragma unroll
  for (int i = 0; i < 3; ++i) {
    int d = tid + i*256;
    float s = 0.f;
    for (int blk = 0; blk < 64; ++blk) s += partial[(size_t)blk*D_ + d];
    pooled[d] = s;  // positive scale factor irrelevant for argmax
  }
  __syncthreads();
  if (tid < E_) {
    float s = 0.f;
    for (int d = 0; d < D_; ++d) s += pooled[d] * rw[d*E_ + tid];
    logits[tid] = s;
  }
  __syncthreads();
  if (tid == 0) {
    int best = 0; float bvv = logits[0];
    for (int e = 1; e < E_; ++e) if (logits[e] > bvv) { bvv = logits[e]; best = e; }
    e_out[0] = best;
  }
}

// ---------------- fp32 -> bf16 convert (n multiple of 2048) ----------------
__global__ void convert_bf16_kernel(const float* __restrict__ src, __bf16* __restrict__ dst) {
  size_t i = ((size_t)blockIdx.x*256 + threadIdx.x)*8;
  __bf16 r[8];
#pragma unroll
  for (int j = 0; j < 8; ++j) r[j] = f2bf(src[i+j]);
  *(bf16x8*)(dst + i) = *(bf16x8*)r;
}

// Wk [L][768][768] fp32 -> rows 768..1535 of wqkv [L][2304][768] bf16
__global__ void convert_wk_kernel(const float* __restrict__ wk, __bf16* __restrict__ wqkv) {
  size_t i = ((size_t)blockIdx.x*256 + threadIdx.x)*8;
  int l = (int)(i / (D_*D_));
  int rem = (int)(i % (D_*D_));
  int n = rem / D_, k = rem % D_;
  __bf16 r[8];
#pragma unroll
  for (int j = 0; j < 8; ++j) r[j] = f2bf(wk[i+j]);
  *(bf16x8*)(wqkv + (size_t)l*2304*D_ + (size_t)(768+n)*D_ + k) = *(bf16x8*)r;
}

// ---------------- TT adapter build: Wq_a / Wv_a -> wqkv bf16 ----------------
__global__ void tt_prep_kernel(
    const float* __restrict__ qc0, const float* __restrict__ qc1, const float* __restrict__ qc2,
    const float* __restrict__ qc3, const float* __restrict__ qc4, const float* __restrict__ qc5,
    const float* __restrict__ vc0, const float* __restrict__ vc1, const float* __restrict__ vc2,
    const float* __restrict__ vc3, const float* __restrict__ vc4, const float* __restrict__ vc5,
    const float* __restrict__ Wq, const float* __restrict__ Wv,
    const int* __restrict__ e_idx, __bf16* __restrict__ wqkv) {
  const int l = blockIdx.x;
  const int pre = blockIdx.y;         // 0 = q, 1 = v
  const int z = blockIdx.z;           // 0..15 -> rows 48z..48z+47
  const int tid = threadIdx.x;
  const int e = e_idx[0];
  const float* c0 = (pre ? vc0 : qc0) + (size_t)(e*L_ + l)*96;   // [12][8]
  const float* c1 = (pre ? vc1 : qc1) + (size_t)(e*L_ + l)*512;  // [8][8][8]
  const float* c2 = (pre ? vc2 : qc2) + (size_t)(e*L_ + l)*512;
  const float* c3 = (pre ? vc3 : qc3) + (size_t)(e*L_ + l)*512;
  const float* c4 = (pre ? vc4 : qc4) + (size_t)(e*L_ + l)*512;
  const float* c5 = (pre ? vc5 : qc5) + (size_t)(e*L_ + l)*96;   // [8][12]
  __shared__ float M1[768];   // [j][l2][m]
  __shared__ float R2[768];   // [q][r][t]
  __shared__ float M2[6144];  // [out][o]
  __shared__ float Rm[6144];  // [o][in]
  for (int idx = tid; idx < 768; idx += 256) {
    int j = idx >> 6, rem = idx & 63, l2 = rem >> 3, m = rem & 7;
    float s = 0.f;
    for (int k = 0; k < 8; ++k) s += c0[j*8 + k] * c1[k*64 + l2*8 + m];
    M1[idx] = s;
    int qq = idx / 96, rem2 = idx % 96, rr = rem2 / 12, t = rem2 % 12;
    float s2 = 0.f;
    for (int si = 0; si < 8; ++si) s2 += c4[qq*64 + rr*8 + si] * c5[si*12 + t];
    R2[idx] = s2;
  }
  __syncthreads();
  for (int idx = tid; idx < 6144; idx += 256) {
    int o = idx & 7, n = (idx >> 3) & 7, jl = idx >> 6;
    float s = 0.f;
    for (int m = 0; m < 8; ++m) s += M1[jl*8 + m] * c2[m*64 + n*8 + o];
    M2[idx] = s;
    int o2 = idx / 768, inp = idx % 768, p = inp / 96, rt = inp % 96;
    float s2 = 0.f;
    for (int qq = 0; qq < 8; ++qq) s2 += c3[o2*64 + p*8 + qq] * R2[qq*96 + rt];
    Rm[idx] = s2;
  }
  __syncthreads();
  const float* Wbase = (pre ? Wv : Wq) + (size_t)l*D_*D_;
  __bf16* dst = wqkv + (size_t)l*2304*D_ + (pre ? (size_t)1536*D_ : 0);
  for (int g = tid; g < 48*96; g += 256) {
    const int outr = z*48 + (g / 96);
    const int inp0 = (g % 96) * 8;
    float m2r[8];
#pragma unroll
    for (int o = 0; o < 8; ++o) m2r[o] = M2[outr*8 + o];
    float acc[8];
#pragma unroll
    for (int u = 0; u < 8; ++u) acc[u] = 0.f;
#pragma unroll
    for (int o = 0; o < 8; ++o) {
      float4 r0 = *(const float4*)&Rm[o*768 + inp0];
      float4 r1 = *(const float4*)&Rm[o*768 + inp0 + 4];
      acc[0] += m2r[o]*r0.x; acc[1] += m2r[o]*r0.y;
      acc[2] += m2r[o]*r0.z; acc[3] += m2r[o]*r0.w;
      acc[4] += m2r[o]*r1.x; acc[5] += m2r[o]*r1.y;
      acc[6] += m2r[o]*r1.z; acc[7] += m2r[o]*r1.w;
    }
    const float* wb = Wbase + (size_t)outr*768 + inp0;
    float4 w0 = *(const float4*)wb;
    float4 w1 = *(const float4*)(wb + 4);
    __bf16 r[8];
    r[0] = f2bf(w0.x + 8.f*acc[0]); r[1] = f2bf(w0.y + 8.f*acc[1]);
    r[2] = f2bf(w0.z + 8.f*acc[2]); r[3] = f2bf(w0.w + 8.f*acc[3]);
    r[4] = f2bf(w1.x + 8.f*acc[4]); r[5] = f2bf(w1.y + 8.f*acc[5]);
    r[6] = f2bf(w1.z + 8.f*acc[6]); r[7] = f2bf(w1.w + 8.f*acc[7]);
    *(bf16x8*)(dst + (size_t)outr*768 + inp0) = *(bf16x8*)r;
  }
}

// ---------------- bf16 MFMA GEMM v4: 256x256 tile, BK=32, ring-2, 2 blocks/CU ----------------
// R8: co-residency + reuse-ratio rewrite.
//  - R7 post-mortem: 112 KiB LDS -> 1 block/CU, 2 waves/SIMD (Occupancy 19%); lockstep
//    barriers left the CU idle on every stall; MfmaUtil stuck ~30%.
//  - Wave-tile 128x64 (8x4 frags): 12 ds_read_b128 -> 32 MFMA = 42.7 FLOP/LDS-byte;
//    per-block K-step is MFMA-bound (1242 vs 1130 cyc LDS).
//  - Ring-2 x 32 KiB = 64 KiB LDS -> 2 blocks/CU, 4 waves/SIMD; the co-resident block
//    covers barrier/vmcnt stalls (m114 TLP mechanism).
//  - One barrier/K-step, late drain: STAGE(t+1) at top (slot freed by previous bar),
//    COMPUTE(t), vmcnt(0) (issue-to-wait = full compute phase > HBM latency), bar.
//    Uniform 4 staging loads/wave: waves 0-3 stage A-lines, waves 4-7 B-lines.
//  - T2 swizzle algebra unchanged (bank conflicts proven 0 in R6/R7).
// Grid: QKV (9,64): x 0-2 = q, 3-5 = k, 6-8 = V-transpose. proj (3,64).
#define SLOT_BYTES 32768
template<bool SPLITV>
__global__ __launch_bounds__(512, 2) void gemm_bt(
    const __bf16* __restrict__ A, const __bf16* __restrict__ Bw,
    const float* __restrict__ bq, const float* __restrict__ bk, const float* __restrict__ bvp,
    __bf16* __restrict__ outb, __bf16* __restrict__ vtout, int Nw) {
  __shared__ __align__(16) char lds[2*SLOT_BYTES];   // 64 KiB -> 2 blocks/CU
  const int tid = threadIdx.x;
  const int w = tid >> 6, lane = tid & 63;
  const int quad = lane >> 4, l16 = lane & 15;
  const int wm = w >> 2, wn = w & 3;
  const size_t mblk = (size_t)blockIdx.y * 256;
  const size_t nblk = (size_t)blockIdx.x * 256;
  const __bf16* Ag = A + mblk * 768;
  const __bf16* Bg = Bw + nblk * 768;

  // ---- staging: waves 0-3 stage A (lines 0..127), waves 4-7 stage B (lines 0..127 of B).
  // Row pairs packed in 128-B lines; slot8 = (row&1)*4 + kseg, phys8 = slot8 ^ (line&7).
  // Swizzle folded into the per-lane GLOBAL source; LDS dest stays linear (rule #21).
  const bool stA = (w < 4);
  int goff[4], loff[4];
#pragma unroll
  for (int i = 0; i < 4; ++i) {
    int lb = (w & 3)*32 + i*8;                    // line base within region
    int line = lb + (lane >> 3);
    int s8 = (lane & 7) ^ (line & 7);
    int row = 2*line + (s8 >> 2);                 // logical row 0..255
    goff[i] = row*768 + (s8 & 3)*8;               // elements
    loff[i] = (stA ? 0 : 16384) + lb*128;         // bytes; HW appends lane*16
  }

  // ---- fragment ds_read byte offsets (swizzled; max 2-way bank aliasing = free)
  int a_foff[8], b_foff[4];
#pragma unroll
  for (int mf = 0; mf < 8; ++mf) {
    int r = wm*128 + mf*16 + l16;
    int line = r >> 1, s8 = (r & 1)*4 + quad, ph = s8 ^ (line & 7);
    a_foff[mf] = line*128 + ph*16;
  }
#pragma unroll
  for (int nf = 0; nf < 4; ++nf) {
    int r = wn*64 + nf*16 + l16;
    int line = r >> 1, s8 = (r & 1)*4 + quad, ph = s8 ^ (line & 7);
    b_foff[nf] = 16384 + line*128 + ph*16;
  }

  floatx4 acc[8][4];
#pragma unroll
  for (int mf = 0; mf < 8; ++mf)
#pragma unroll
    for (int nf = 0; nf < 4; ++nf) acc[mf][nf] = {0.f,0.f,0.f,0.f};

  auto STAGE = [&](int t) {
    const __bf16* Gb = (stA ? Ag : Bg) + t*32;
    char* ls = lds + (t & 1)*SLOT_BYTES;
#pragma unroll
    for (int i = 0; i < 4; ++i) async16(Gb + goff[i], ls + loff[i]);
  };

  auto COMPUTE = [&](int t) {
    const char* ls = lds + (t & 1)*SLOT_BYTES;
    bf16x8 af[8], bfr[4];
#pragma unroll
    for (int nf = 0; nf < 4; ++nf) bfr[nf] = *(const bf16x8*)(ls + b_foff[nf]);
#pragma unroll
    for (int mf = 0; mf < 8; ++mf) af[mf] = *(const bf16x8*)(ls + a_foff[mf]);
    __builtin_amdgcn_s_setprio(1);
#pragma unroll
    for (int mf = 0; mf < 8; ++mf)
#pragma unroll
      for (int nf = 0; nf < 4; ++nf)
        acc[mf][nf] = __builtin_amdgcn_mfma_f32_16x16x32_bf16(af[mf], bfr[nf], acc[mf][nf], 0, 0, 0);
    __builtin_amdgcn_s_setprio(0);
  };

  // ---- prologue: stage tile 0, validate
  STAGE(0);
  asm volatile("s_waitcnt vmcnt(0)" ::: "memory");
  __builtin_amdgcn_s_barrier();
  __builtin_amdgcn_sched_barrier(0);

  // ---- main loop: 24 K-steps, one barrier each.
  // STAGE(t+1) overwrites slot (t+1)&1, freed by the barrier ending iter t-1.
  // vmcnt(0) validates t+1 after a full compute phase of issue-to-wait distance.
  for (int t = 0; t < 24; ++t) {
    if (t < 23) STAGE(t + 1);
    COMPUTE(t);
    if (t < 23) {
      asm volatile("s_waitcnt vmcnt(0)" ::: "memory");
      __builtin_amdgcn_s_barrier();
      __builtin_amdgcn_sched_barrier(0);
    }
  }

  // ---- epilogue
  if (SPLITV && blockIdx.x >= 6) {
    // V region (cols 1536..2303): bias + transpose-write into vt[bh][64][512]
#pragma unroll
    for (int nf = 0; nf < 4; ++nf) {
      const int vcol = (int)nblk - 1536 + wn*64 + nf*16 + l16;   // 0..767
      const int h = vcol >> 6, d = vcol & 63;
      const float bval = bvp[vcol];
#pragma unroll
      for (int mf = 0; mf < 8; ++mf) {
        const int mrow = (int)mblk + wm*128 + mf*16 + quad*4;    // r=0 base
        const int b = mrow >> 9, s = mrow & 511;
        __bf16 pr[4];
#pragma unroll
        for (int r = 0; r < 4; ++r) pr[r] = f2bf(acc[mf][nf][r] + bval);
        *(bf16x4*)(vtout + (size_t)((b*H_ + h)*64 + d)*S_ + s) = *(bf16x4*)pr;
      }
    }
    return;
  }
  const float* bias = bq;
  if (SPLITV) bias = (blockIdx.x < 3) ? bq : bk;
  float bval[4]; int ncol[4];
#pragma unroll
  for (int nf = 0; nf < 4; ++nf) {
    ncol[nf] = (int)nblk + wn*64 + nf*16 + l16;
    int bc = ncol[nf]; if (bc >= 768) bc -= 768;
    bval[nf] = bias[bc];
  }
#pragma unroll
  for (int mf = 0; mf < 8; ++mf) {
#pragma unroll
    for (int nf = 0; nf < 4; ++nf) {
#pragma unroll
      for (int r = 0; r < 4; ++r) {
        const int mrow = (int)mblk + wm*128 + mf*16 + quad*4 + r;
        outb[(size_t)mrow*Nw + ncol[nf]] = f2bf(acc[mf][nf][r] + bval[nf]);
      }
    }
  }
}

// ---------------- flash attention v2 (R4-proven): S^T-mfma, padded LDS, XCD swizzle ----------------
// 1-D grid of 3072: n&7 selects XCD-slot; bh = (n>>6)*8 + (n&7); qtile = (n>>3)&7.
#define PSTR 72   // padded LDS row stride (bf16): 144 B -> bank-even b128 access
__global__ __launch_bounds__(256) void flash_kernel(const __bf16* __restrict__ qkv,
                                                    const __bf16* __restrict__ vt,
                                                    __bf16* __restrict__ ctx) {
  __shared__ __align__(16) __bf16 Qs[64*PSTR];    // [q][d]
  __shared__ __align__(16) __bf16 Ks[64*PSTR];    // [kv][d]
  __shared__ __align__(16) __bf16 Vts[64*PSTR];   // [d][kv]
  __shared__ __align__(16) __bf16 Ps[64*PSTR];    // [q][kv], wave w owns rows w*16..+15
  const int tid = threadIdx.x;
  const int w = tid >> 6, lane = tid & 63;
  const int quad = lane >> 4, l16 = lane & 15;
  const int n = blockIdx.x;
  const int bh = (n >> 6)*8 + (n & 7);
  const int q0 = ((n >> 3) & 7) * 64;
  const int b = bh / H_, h = bh % H_;
  const float SCL = 0.125f * 1.44269504f;  // 1/sqrt(64) * log2(e)

  {
#pragma unroll
    for (int it = 0; it < 2; ++it) {
      int slot = it*256 + tid, row = slot >> 3, seg = slot & 7;
      bf16x8 v = *(const bf16x8*)(qkv + (size_t)(b*S_ + q0 + row)*2304 + h*64 + seg*8);
      *(bf16x8*)&Qs[row*PSTR + seg*8] = v;
    }
  }

  floatx4 acc_o[4];   // C[m=q_local=quad*4+r][n=d=jd*16+l16]
#pragma unroll
  for (int jd = 0; jd < 4; ++jd) acc_o[jd] = {0.f,0.f,0.f,0.f};
  float m_prev = -__builtin_inff();   // per-lane q = w*16 + l16 (log2 domain)
  float l_part = 0.f;                 // per-quad partial of the softmax denom

  for (int kt = 0; kt < 8; ++kt) {
    __syncthreads();
#pragma unroll
    for (int it = 0; it < 2; ++it) {
      int slot = it*256 + tid, row = slot >> 3, seg = slot & 7;
      bf16x8 kvv = *(const bf16x8*)(qkv + (size_t)(b*S_ + kt*64 + row)*2304 + 768 + h*64 + seg*8);
      bf16x8 vtv = *(const bf16x8*)(vt + (size_t)(bh*64 + row)*S_ + kt*64 + seg*8);
      *(bf16x8*)&Ks[row*PSTR + seg*8] = kvv;
      *(bf16x8*)&Vts[row*PSTR + seg*8] = vtv;
    }
    __syncthreads();
    // S^T tile: mfma(A=K, B=Q) -> C[m=kv=i*16+quad*4+r][n=q=w*16+l16]
    floatx4 sacc[4];
#pragma unroll
    for (int i = 0; i < 4; ++i) sacc[i] = {0.f,0.f,0.f,0.f};
#pragma unroll
    for (int kk = 0; kk < 64; kk += 32) {
      bf16x8 bq_ = *(const bf16x8*)&Qs[(w*16 + l16)*PSTR + kk + quad*8];
#pragma unroll
      for (int i = 0; i < 4; ++i) {
        bf16x8 ak = *(const bf16x8*)&Ks[(i*16 + l16)*PSTR + kk + quad*8];
        sacc[i] = __builtin_amdgcn_mfma_f32_16x16x32_bf16(ak, bq_, sacc[i], 0, 0, 0);
      }
    }
    float sv[4][4];
#pragma unroll
    for (int i = 0; i < 4; ++i)
#pragma unroll
      for (int r = 0; r < 4; ++r) sv[i][r] = sacc[i][r] * SCL;
    float mloc = sv[0][0];
#pragma unroll
    for (int i = 0; i < 4; ++i)
#pragma unroll
      for (int r = 0; r < 4; ++r) mloc = fmaxf(mloc, sv[i][r]);
    mloc = fmaxf(mloc, __shfl_xor(mloc, 16));
    mloc = fmaxf(mloc, __shfl_xor(mloc, 32));
    float mnew = fmaxf(m_prev, mloc);
    float alpha = fexp2(m_prev - mnew);
    m_prev = mnew;
    float rsum = 0.f;
#pragma unroll
    for (int i = 0; i < 4; ++i) {
      __bf16 pr[4];
#pragma unroll
      for (int r = 0; r < 4; ++r) {
        float p = fexp2(sv[i][r] - mnew);
        rsum += p;
        pr[r] = f2bf(p);
      }
      *(bf16x4*)&Ps[(w*16 + l16)*PSTR + i*16 + quad*4] = *(bf16x4*)pr;  // b64, bank-even
    }
    l_part = l_part*alpha + rsum;
    float ab[4];
#pragma unroll
    for (int r = 0; r < 4; ++r) ab[r] = __shfl(alpha, quad*4 + r);
#pragma unroll
    for (int jd = 0; jd < 4; ++jd)
#pragma unroll
      for (int r = 0; r < 4; ++r) acc_o[jd][r] *= ab[r];
    // O += P V : same-wave ds write->read is in-order
#pragma unroll
    for (int kk = 0; kk < 64; kk += 32) {
      bf16x8 ap = *(const bf16x8*)&Ps[(w*16 + l16)*PSTR + kk + quad*8];
#pragma unroll
      for (int jd = 0; jd < 4; ++jd) {
        bf16x8 bv_ = *(const bf16x8*)&Vts[(jd*16 + l16)*PSTR + kk + quad*8];
        acc_o[jd] = __builtin_amdgcn_mfma_f32_16x16x32_bf16(ap, bv_, acc_o[jd], 0, 0, 0);
      }
    }
  }
  float l_tot = l_part;
  l_tot += __shfl_xor(l_tot, 16);
  l_tot += __shfl_xor(l_tot, 32);
  float lb[4];
#pragma unroll
  for (int r = 0; r < 4; ++r) lb[r] = __shfl(l_tot, quad*4 + r);
#pragma unroll
  for (int jd = 0; jd < 4; ++jd) {
    const int d = jd*16 + l16;
#pragma unroll
    for (int r = 0; r < 4; ++r) {
      const int q = q0 + w*16 + quad*4 + r;
      ctx[(size_t)(b*S_ + q)*D_ + h*64 + d] = f2bf(acc_o[jd][r] / lb[r]);
    }
  }
}

// ---------------- residual + LayerNorm v2: wave-per-row, bf16 master chain ----------------
// 4 rows/block (one wave each), bf16x8 loads, shuffle-only reduction (no LDS/barrier).
// Lane covers cols lane*8..+7 (all lanes) and 512+lane*8..+7 (lanes<32).
// FIRST: residual read from fp32 hidden. LAST: write fp32 to d_out; else bf16 in-place xb.
template<bool FIRST, bool LAST>
__global__ __launch_bounds__(256) void ln_kernel(const float* __restrict__ residf,
                                                 __bf16* xb,           // resid in (l>0) + out (l<11); in-place
                                                 const __bf16* __restrict__ proj,
                                                 const float* __restrict__ gamma,
                                                 const float* __restrict__ beta,
                                                 float* __restrict__ xoutf) {
  const int tid = threadIdx.x;
  const int w = tid >> 6, lane = tid & 63;
  const int row = blockIdx.x*4 + w;
  const size_t base = (size_t)row * D_;
  const int c0 = lane*8;
  const bool has2 = lane < 32;
  const int c1 = 512 + lane*8;

  float v0[8], v1[8];
  {
    bf16x8 p0 = *(const bf16x8*)(proj + base + c0);
    if (FIRST) {
      float4 a = *(const float4*)(residf + base + c0);
      float4 bq4 = *(const float4*)(residf + base + c0 + 4);
      v0[0]=a.x+(float)p0[0]; v0[1]=a.y+(float)p0[1]; v0[2]=a.z+(float)p0[2]; v0[3]=a.w+(float)p0[3];
      v0[4]=bq4.x+(float)p0[4]; v0[5]=bq4.y+(float)p0[5]; v0[6]=bq4.z+(float)p0[6]; v0[7]=bq4.w+(float)p0[7];
    } else {
      bf16x8 r0 = *(const bf16x8*)(xb + base + c0);
#pragma unroll
      for (int j = 0; j < 8; ++j) v0[j] = (float)r0[j] + (float)p0[j];
    }
    if (has2) {
      bf16x8 p1 = *(const bf16x8*)(proj + base + c1);
      if (FIRST) {
        float4 a = *(const float4*)(residf + base + c1);
        float4 bq4 = *(const float4*)(residf + base + c1 + 4);
        v1[0]=a.x+(float)p1[0]; v1[1]=a.y+(float)p1[1]; v1[2]=a.z+(float)p1[2]; v1[3]=a.w+(float)p1[3];
        v1[4]=bq4.x+(float)p1[4]; v1[5]=bq4.y+(float)p1[5]; v1[6]=bq4.z+(float)p1[6]; v1[7]=bq4.w+(float)p1[7];
      } else {
        bf16x8 r1 = *(const bf16x8*)(xb + base + c1);
#pragma unroll
        for (int j = 0; j < 8; ++j) v1[j] = (float)r1[j] + (float)p1[j];
      }
    } else {
#pragma unroll
      for (int j = 0; j < 8; ++j) v1[j] = 0.f;
    }
  }
  float s = 0.f;
#pragma unroll
  for (int j = 0; j < 8; ++j) s += v0[j] + v1[j];
#pragma unroll
  for (int off = 32; off; off >>= 1) s += __shfl_xor(s, off);
  const float mu = s * (1.f/768.f);
  float q = 0.f;
#pragma unroll
  for (int j = 0; j < 8; ++j) { float d0 = v0[j]-mu; q += d0*d0; }
  if (has2) {
#pragma unroll
    for (int j = 0; j < 8; ++j) { float d1 = v1[j]-mu; q += d1*d1; }
  }
#pragma unroll
  for (int off = 32; off; off >>= 1) q += __shfl_xor(q, off);
  const float rs = rsqrtf(q * (1.f/768.f) + 1e-12f);

  {
    float4 g0 = *(const float4*)(gamma + c0);
    float4 g1 = *(const float4*)(gamma + c0 + 4);
    float4 b0 = *(const float4*)(beta + c0);
    float4 b1 = *(const float4*)(beta + c0 + 4);
    float o[8];
    o[0]=(v0[0]-mu)*rs*g0.x+b0.x; o[1]=(v0[1]-mu)*rs*g0.y+b0.y;
    o[2]=(v0[2]-mu)*rs*g0.z+b0.z; o[3]=(v0[3]-mu)*rs*g0.w+b0.w;
    o[4]=(v0[4]-mu)*rs*g1.x+b1.x; o[5]=(v0[5]-mu)*rs*g1.y+b1.y;
    o[6]=(v0[6]-mu)*rs*g1.z+b1.z; o[7]=(v0[7]-mu)*rs*g1.w+b1.w;
    if (LAST) {
      *(float4*)(xoutf + base + c0)     = {o[0],o[1],o[2],o[3]};
      *(float4*)(xoutf + base + c0 + 4) = {o[4],o[5],o[6],o[7]};
    } else {
      __bf16 ob[8];
#pragma unroll
      for (int j = 0; j < 8; ++j) ob[j] = f2bf(o[j]);
      *(bf16x8*)(xb + base + c0) = *(bf16x8*)ob;
    }
  }
  if (has2) {
    float4 g0 = *(const float4*)(gamma + c1);
    float4 g1 = *(const float4*)(gamma + c1 + 4);
    float4 b0 = *(const float4*)(beta + c1);
    float4 b1 = *(const float4*)(beta + c1 + 4);
    float o[8];
    o[0]=(v1[0]-mu)*rs*g0.x+b0.x; o[1]=(v1[1]-mu)*rs*g0.y+b0.y;
    o[2]=(v1[2]-mu)*rs*g0.z+b0.z; o[3]=(v1[3]-mu)*rs*g0.w+b0.w;
    o[4]=(v1[4]-mu)*rs*g1.x+b1.x; o[5]=(v1[5]-mu)*rs*g1.y+b1.y;
    o[6]=(v1[6]-mu)*rs*g1.z+b1.z; o[7]=(v1[7]-mu)*rs*g1.w+b1.w;
    if (LAST) {
      *(float4*)(xoutf + base + c1)     = {o[0],o[1],o[2],o[3]};
      *(float4*)(xoutf + base + c1 + 4) = {o[4],o[5],o[6],o[7]};
    } else {
      __bf16 ob[8];
#pragma unroll
      for (int j = 0; j < 8; ++j) ob[j] = f2bf(o[j]);
      *(bf16x8*)(xb + base + c1) = *(bf16x8*)ob;
    }
  }
}

extern "C" void kernel_launch(void* const* d_in, const int* in_sizes, int n_in,
                              void* d_out, int out_size, void* d_ws, size_t ws_size,
                              hipStream_t stream) {
  const float* hidden = (const float*)d_in[0];
  const float* router = (const float*)d_in[1];
  const float* qc[6]; const float* vc[6];
  for (int i = 0; i < 6; ++i) qc[i] = (const float*)d_in[2+i];
  for (int i = 0; i < 6; ++i) vc[i] = (const float*)d_in[8+i];
  const float* Wq = (const float*)d_in[14];
  const float* Wk = (const float*)d_in[15];
  const float* Wv = (const float*)d_in[16];
  const float* Wo = (const float*)d_in[17];
  const float* bq = (const float*)d_in[18];
  const float* bk = (const float*)d_in[19];
  const float* bv = (const float*)d_in[20];
  const float* bo = (const float*)d_in[21];
  const float* lns = (const float*)d_in[22];
  const float* lnb = (const float*)d_in[23];
  float* out = (float*)d_out;

  char* ws = (char*)d_ws;
  size_t off = 0;
  auto alloc = [&](size_t bytes) -> void* {
    off = (off + 255) & ~(size_t)255;
    void* p = ws + off; off += bytes; return p;
  };
  int*    e_idx = (int*)   alloc(4);
  float*  rpart = (float*) alloc((size_t)64*D_*4);
  __bf16* xbf   = (__bf16*)alloc((size_t)BS_*D_*2);
  __bf16* qkv   = (__bf16*)alloc((size_t)BS_*2304*2);
  __bf16* vt    = (__bf16*)alloc((size_t)B_*H_*64*S_*2);
  __bf16* ctx   = (__bf16*)alloc((size_t)BS_*D_*2);
  __bf16* projb = (__bf16*)alloc((size_t)BS_*D_*2);
  __bf16* wqkv  = (__bf16*)alloc((size_t)L_*2304*D_*2);
  __bf16* wobf  = (__bf16*)alloc((size_t)L_*D_*D_*2);
  (void)ws_size; (void)in_sizes; (void)n_in; (void)out_size;

  routing_pool_kernel<<<64, 256, 0, stream>>>(hidden, rpart);
  routing_finish_kernel<<<1, 256, 0, stream>>>(rpart, router, e_idx);
  convert_bf16_kernel<<<(BS_*D_)/2048, 256, 0, stream>>>(hidden, xbf);
  tt_prep_kernel<<<dim3(L_, 2, 16), 256, 0, stream>>>(qc[0],qc[1],qc[2],qc[3],qc[4],qc[5],
                                                      vc[0],vc[1],vc[2],vc[3],vc[4],vc[5],
                                                      Wq, Wv, e_idx, wqkv);
  convert_wk_kernel<<<(L_*D_*D_)/2048, 256, 0, stream>>>(Wk, wqkv);
  convert_bf16_kernel<<<(L_*D_*D_)/2048, 256, 0, stream>>>(Wo, wobf);

  for (int l = 0; l < L_; ++l) {
    gemm_bt<true><<<dim3(9,64), 512, 0, stream>>>(xbf, wqkv + (size_t)l*2304*D_,
        bq + l*D_, bk + l*D_, bv + l*D_, qkv, vt, 2304);
    flash_kernel<<<3072, 256, 0, stream>>>(qkv, vt, ctx);
    gemm_bt<false><<<dim3(3,64), 512, 0, stream>>>(ctx, wobf + (size_t)l*D_*D_,
        bo + l*D_, nullptr, nullptr, projb, nullptr, 768);
    if (l == 0)
      ln_kernel<true,false><<<BS_/4, 256, 0, stream>>>(hidden, xbf, projb,
          lns + l*D_, lnb + l*D_, nullptr);
    else if (l == L_-1)
      ln_kernel<false,true><<<BS_/4, 256, 0, stream>>>(nullptr, xbf, projb,
          lns + l*D_, lnb + l*D_, out);
    else
      ln_kernel<false,false><<<BS_/4, 256, 0, stream>>>(nullptr, xbf, projb,
          lns + l*D_, lnb + l*D_, nullptr);
  }
}

// Round 4
// 2446.106 us; speedup vs baseline: 1.0822x; 1.0822x over previous
//
#include <hip/hip_runtime.h>
#include <hip/hip_bf16.h>
#include <stdint.h>

#define E_ 8
#define L_ 12
#define D_ 768
#define H_ 12
#define S_ 512
#define B_ 32
#define BS_ (B_*S_)   // 16384

typedef __attribute__((ext_vector_type(4))) float floatx4;
typedef __attribute__((ext_vector_type(8))) __bf16 bf16x8;
typedef __attribute__((ext_vector_type(4))) __bf16 bf16x4;

__device__ __forceinline__ __bf16 f2bf(float f) {
  unsigned u = __builtin_bit_cast(unsigned, f);
  u += 0x7fffu + ((u >> 16) & 1u);           // RNE
  unsigned short h = (unsigned short)(u >> 16);
  return __builtin_bit_cast(__bf16, h);
}

__device__ __forceinline__ float fexp2(float x) {
#if __has_builtin(__builtin_amdgcn_exp2f)
  return __builtin_amdgcn_exp2f(x);
#else
  return exp2f(x);
#endif
}

__device__ __forceinline__ void async16(const void* g, void* l) {
  __builtin_amdgcn_global_load_lds((__attribute__((address_space(1))) void*)g,
                                   (__attribute__((address_space(3))) void*)l,
                                   16, 0, 0);
}

// ---------------- routing stage 1: 64 blocks x 8 rows, coalesced partial sums ----------------
__global__ void routing_pool_kernel(const float* __restrict__ hidden,
                                    float* __restrict__ partial) {
  const int blk = blockIdx.x;    // 0..63
  const int tid = threadIdx.x;
  const float* base = hidden + (size_t)(B_-1)*S_*D_ + (size_t)blk*8*D_;
  float acc[3] = {0.f, 0.f, 0.f};
  for (int s = 0; s < 8; ++s) {
#pragma unroll
    for (int i = 0; i < 3; ++i)
      acc[i] += base[(size_t)s*D_ + tid + i*256];
  }
#pragma unroll
  for (int i = 0; i < 3; ++i) partial[(size_t)blk*D_ + tid + i*256] = acc[i];
}

// ---------------- routing stage 2: reduce partials, logits, argmax ----------------
__global__ void routing_finish_kernel(const float* __restrict__ partial,
                                      const float* __restrict__ rw,
                                      int* __restrict__ e_out) {
  __shared__ float pooled[D_];
  __shared__ float logits[E_];
  int tid = threadIdx.x;
#pragma unroll
  for (int i = 0; i < 3; ++i) {
    int d = tid + i*256;
    float s = 0.f;
    for (int blk = 0; blk < 64; ++blk) s += partial[(size_t)blk*D_ + d];
    pooled[d] = s;  // positive scale factor irrelevant for argmax
  }
  __syncthreads();
  if (tid < E_) {
    float s = 0.f;
    for (int d = 0; d < D_; ++d) s += pooled[d] * rw[d*E_ + tid];
    logits[tid] = s;
  }
  __syncthreads();
  if (tid == 0) {
    int best = 0; float bvv = logits[0];
    for (int e = 1; e < E_; ++e) if (logits[e] > bvv) { bvv = logits[e]; best = e; }
    e_out[0] = best;
  }
}

// ---------------- fp32 -> bf16 convert (n multiple of 2048) ----------------
__global__ void convert_bf16_kernel(const float* __restrict__ src, __bf16* __restrict__ dst) {
  size_t i = ((size_t)blockIdx.x*256 + threadIdx.x)*8;
  __bf16 r[8];
#pragma unroll
  for (int j = 0; j < 8; ++j) r[j] = f2bf(src[i+j]);
  *(bf16x8*)(dst + i) = *(bf16x8*)r;
}

// Wk [L][768][768] fp32 -> rows 768..1535 of wqkv [L][2304][768] bf16
__global__ void convert_wk_kernel(const float* __restrict__ wk, __bf16* __restrict__ wqkv) {
  size_t i = ((size_t)blockIdx.x*256 + threadIdx.x)*8;
  int l = (int)(i / (D_*D_));
  int rem = (int)(i % (D_*D_));
  int n = rem / D_, k = rem % D_;
  __bf16 r[8];
#pragma unroll
  for (int j = 0; j < 8; ++j) r[j] = f2bf(wk[i+j]);
  *(bf16x8*)(wqkv + (size_t)l*2304*D_ + (size_t)(768+n)*D_ + k) = *(bf16x8*)r;
}

// ---------------- TT adapter build: Wq_a / Wv_a -> wqkv bf16 ----------------
__global__ void tt_prep_kernel(
    const float* __restrict__ qc0, const float* __restrict__ qc1, const float* __restrict__ qc2,
    const float* __restrict__ qc3, const float* __restrict__ qc4, const float* __restrict__ qc5,
    const float* __restrict__ vc0, const float* __restrict__ vc1, const float* __restrict__ vc2,
    const float* __restrict__ vc3, const float* __restrict__ vc4, const float* __restrict__ vc5,
    const float* __restrict__ Wq, const float* __restrict__ Wv,
    const int* __restrict__ e_idx, __bf16* __restrict__ wqkv) {
  const int l = blockIdx.x;
  const int pre = blockIdx.y;         // 0 = q, 1 = v
  const int z = blockIdx.z;           // 0..15 -> rows 48z..48z+47
  const int tid = threadIdx.x;
  const int e = e_idx[0];
  const float* c0 = (pre ? vc0 : qc0) + (size_t)(e*L_ + l)*96;   // [12][8]
  const float* c1 = (pre ? vc1 : qc1) + (size_t)(e*L_ + l)*512;  // [8][8][8]
  const float* c2 = (pre ? vc2 : qc2) + (size_t)(e*L_ + l)*512;
  const float* c3 = (pre ? vc3 : qc3) + (size_t)(e*L_ + l)*512;
  const float* c4 = (pre ? vc4 : qc4) + (size_t)(e*L_ + l)*512;
  const float* c5 = (pre ? vc5 : qc5) + (size_t)(e*L_ + l)*96;   // [8][12]
  __shared__ float M1[768];   // [j][l2][m]
  __shared__ float R2[768];   // [q][r][t]
  __shared__ float M2[6144];  // [out][o]
  __shared__ float Rm[6144];  // [o][in]
  for (int idx = tid; idx < 768; idx += 256) {
    int j = idx >> 6, rem = idx & 63, l2 = rem >> 3, m = rem & 7;
    float s = 0.f;
    for (int k = 0; k < 8; ++k) s += c0[j*8 + k] * c1[k*64 + l2*8 + m];
    M1[idx] = s;
    int qq = idx / 96, rem2 = idx % 96, rr = rem2 / 12, t = rem2 % 12;
    float s2 = 0.f;
    for (int si = 0; si < 8; ++si) s2 += c4[qq*64 + rr*8 + si] * c5[si*12 + t];
    R2[idx] = s2;
  }
  __syncthreads();
  for (int idx = tid; idx < 6144; idx += 256) {
    int o = idx & 7, n = (idx >> 3) & 7, jl = idx >> 6;
    float s = 0.f;
    for (int m = 0; m < 8; ++m) s += M1[jl*8 + m] * c2[m*64 + n*8 + o];
    M2[idx] = s;
    int o2 = idx / 768, inp = idx % 768, p = inp / 96, rt = inp % 96;
    float s2 = 0.f;
    for (int qq = 0; qq < 8; ++qq) s2 += c3[o2*64 + p*8 + qq] * R2[qq*96 + rt];
    Rm[idx] = s2;
  }
  __syncthreads();
  const float* Wbase = (pre ? Wv : Wq) + (size_t)l*D_*D_;
  __bf16* dst = wqkv + (size_t)l*2304*D_ + (pre ? (size_t)1536*D_ : 0);
  for (int g = tid; g < 48*96; g += 256) {
    const int outr = z*48 + (g / 96);
    const int inp0 = (g % 96) * 8;
    float m2r[8];
#pragma unroll
    for (int o = 0; o < 8; ++o) m2r[o] = M2[outr*8 + o];
    float acc[8];
#pragma unroll
    for (int u = 0; u < 8; ++u) acc[u] = 0.f;
#pragma unroll
    for (int o = 0; o < 8; ++o) {
      float4 r0 = *(const float4*)&Rm[o*768 + inp0];
      float4 r1 = *(const float4*)&Rm[o*768 + inp0 + 4];
      acc[0] += m2r[o]*r0.x; acc[1] += m2r[o]*r0.y;
      acc[2] += m2r[o]*r0.z; acc[3] += m2r[o]*r0.w;
      acc[4] += m2r[o]*r1.x; acc[5] += m2r[o]*r1.y;
      acc[6] += m2r[o]*r1.z; acc[7] += m2r[o]*r1.w;
    }
    const float* wb = Wbase + (size_t)outr*768 + inp0;
    float4 w0 = *(const float4*)wb;
    float4 w1 = *(const float4*)(wb + 4);
    __bf16 r[8];
    r[0] = f2bf(w0.x + 8.f*acc[0]); r[1] = f2bf(w0.y + 8.f*acc[1]);
    r[2] = f2bf(w0.z + 8.f*acc[2]); r[3] = f2bf(w0.w + 8.f*acc[3]);
    r[4] = f2bf(w1.x + 8.f*acc[4]); r[5] = f2bf(w1.y + 8.f*acc[5]);
    r[6] = f2bf(w1.z + 8.f*acc[6]); r[7] = f2bf(w1.w + 8.f*acc[7]);
    *(bf16x8*)(dst + (size_t)outr*768 + inp0) = *(bf16x8*)r;
  }
}

// ---------------- bf16 MFMA GEMM v3 (R7-proven best): 256x192, BK=32, ring-4, split clusters ----------------
// R9: reverted verbatim from R7 (79 us QKV). R8's 256x256 ring-2 regressed (96.7 us):
// bad grid quantization (576 blocks @2/CU = 1.125 rounds) + vmcnt(0) full-drain killed
// the depth-3 prefetch. Keep: ring-4 slots, prefetch distance 3, counted vmcnt (never 0
// in main loop), T2 line-XOR swizzle (bank conflicts = 0), split 12-MFMA clusters, T5.
// Grid: QKV (12,64) = 768 blocks = exactly 3 CU rounds; proj (4,64) = 1 round.
#define SLOT_BYTES 28672
template<bool SPLITV>
__global__ __launch_bounds__(512, 2) void gemm_bt(
    const __bf16* __restrict__ A, const __bf16* __restrict__ Bw,
    const float* __restrict__ bq, const float* __restrict__ bk, const float* __restrict__ bvp,
    __bf16* __restrict__ outb, __bf16* __restrict__ vtout, int Nw) {
  __shared__ __align__(16) char lds[4*SLOT_BYTES];   // 112 KiB
  const int tid = threadIdx.x;
  const int w = tid >> 6, lane = tid & 63;
  const int quad = lane >> 4, l16 = lane & 15;
  const int wm = w >> 2, wn = w & 3;
  const size_t mblk = (size_t)blockIdx.y * 256;
  const size_t nblk = (size_t)blockIdx.x * 192;
  const __bf16* Ag = A + mblk * 768;
  const __bf16* Bg = Bw + nblk * 768;

  // ---- staging descriptors: per-lane pre-swizzled global offsets, wave-uniform LDS bases
  int a_goff[2], a_loff[2];
#pragma unroll
  for (int i = 0; i < 2; ++i) {
    int line = w*16 + i*8 + (lane >> 3);          // A line 0..127
    int s8 = (lane & 7) ^ (line & 7);
    int row = 2*line + (s8 >> 2);                 // logical A row 0..255
    a_goff[i] = row*768 + (s8 & 3)*8;             // elements
    a_loff[i] = (w*16 + i*8)*128;                 // bytes; HW appends lane*16
  }
  int b_goff[2], b_loff[2];
#pragma unroll
  for (int i = 0; i < 2; ++i) {
    int bl0 = (w < 4) ? (w*16 + i*8) : (64 + (w-4)*8);   // B line base (0..95)
    int line = bl0 + (lane >> 3);
    int s8 = (lane & 7) ^ (line & 7);
    int row = 2*line + (s8 >> 2);                 // logical B row 0..191
    b_goff[i] = row*768 + (s8 & 3)*8;
    b_loff[i] = 16384 + bl0*128;                  // B region starts at 16 KiB
  }

  // ---- fragment ds_read byte offsets (swizzled; 2-way max bank aliasing)
  int a_foff[8], b_foff[3];
#pragma unroll
  for (int mf = 0; mf < 8; ++mf) {
    int r = wm*128 + mf*16 + l16;
    int line = r >> 1, s8 = (r & 1)*4 + quad, ph = s8 ^ (line & 7);
    a_foff[mf] = line*128 + ph*16;
  }
#pragma unroll
  for (int nf = 0; nf < 3; ++nf) {
    int r = wn*48 + nf*16 + l16;
    int line = r >> 1, s8 = (r & 1)*4 + quad, ph = s8 ^ (line & 7);
    b_foff[nf] = 16384 + line*128 + ph*16;
  }

  floatx4 acc[8][3];
#pragma unroll
  for (int mf = 0; mf < 8; ++mf)
#pragma unroll
    for (int nf = 0; nf < 3; ++nf) acc[mf][nf] = {0.f,0.f,0.f,0.f};

  auto STAGE = [&](int t) {
    const __bf16* Ab = Ag + t*32;
    const __bf16* Bb = Bg + t*32;
    char* ls = lds + (t & 3)*SLOT_BYTES;
    async16(Ab + a_goff[0], ls + a_loff[0]);
    async16(Ab + a_goff[1], ls + a_loff[1]);
    if (w < 4) {
      async16(Bb + b_goff[0], ls + b_loff[0]);
      async16(Bb + b_goff[1], ls + b_loff[1]);
    } else {
      async16(Bb + b_goff[0], ls + b_loff[0]);
    }
  };

  bf16x8 af[8], bfr[3];
  auto LOAD1 = [&](int u) {
    const char* ls = lds + (u & 3)*SLOT_BYTES;
#pragma unroll
    for (int nf = 0; nf < 3; ++nf) bfr[nf] = *(const bf16x8*)(ls + b_foff[nf]);
#pragma unroll
    for (int mf = 0; mf < 4; ++mf) af[mf] = *(const bf16x8*)(ls + a_foff[mf]);
  };
  auto LOAD2 = [&](int u) {
    const char* ls = lds + (u & 3)*SLOT_BYTES;
#pragma unroll
    for (int mf = 4; mf < 8; ++mf) af[mf] = *(const bf16x8*)(ls + a_foff[mf]);
  };
  auto MM = [&](int mf0) {
    __builtin_amdgcn_s_setprio(1);
#pragma unroll
    for (int mf = mf0; mf < mf0 + 4; ++mf)
#pragma unroll
      for (int nf = 0; nf < 3; ++nf)
        acc[mf][nf] = __builtin_amdgcn_mfma_f32_16x16x32_bf16(af[mf], bfr[nf], acc[mf][nf], 0, 0, 0);
    __builtin_amdgcn_s_setprio(0);
  };
  auto BAR = [&]() {
    __builtin_amdgcn_s_barrier();
    __builtin_amdgcn_sched_barrier(0);
  };

  // ---- prologue: 3 subtiles in flight; validate subtile 0
  STAGE(0); STAGE(1); STAGE(2);
  if (w < 4) asm volatile("s_waitcnt vmcnt(8)" ::: "memory");
  else       asm volatile("s_waitcnt vmcnt(6)" ::: "memory");
  BAR();

  // ---- main loop: u = 0..20 (STAGE(u+3) valid, steady vmcnt)
  for (int u = 0; u < 21; ++u) {
    LOAD1(u);
    BAR();
    MM(0);
    LOAD2(u);
    STAGE(u + 3);
    if (w < 4) asm volatile("s_waitcnt vmcnt(8)" ::: "memory");
    else       asm volatile("s_waitcnt vmcnt(6)" ::: "memory");
    BAR();
    MM(4);
  }
  // ---- u = 21: no stage; validate 22
  LOAD1(21);
  BAR();
  MM(0);
  LOAD2(21);
  if (w < 4) asm volatile("s_waitcnt vmcnt(4)" ::: "memory");
  else       asm volatile("s_waitcnt vmcnt(3)" ::: "memory");
  BAR();
  MM(4);
  // ---- u = 22: validate 23
  LOAD1(22);
  BAR();
  MM(0);
  LOAD2(22);
  asm volatile("s_waitcnt vmcnt(0)" ::: "memory");
  BAR();
  MM(4);
  // ---- u = 23: final
  LOAD1(23);
  BAR();
  MM(0);
  LOAD2(23);
  BAR();
  MM(4);

  // ---- epilogue
  if (SPLITV && blockIdx.x >= 8) {
    // V region (cols 1536..2303): bias + transpose-write into vt[bh][64][512]
#pragma unroll
    for (int nf = 0; nf < 3; ++nf) {
      const int vcol = (int)nblk - 1536 + wn*48 + nf*16 + l16;   // 0..767
      const int h = vcol >> 6, d = vcol & 63;
      const float bval = bvp[vcol];
#pragma unroll
      for (int mf = 0; mf < 8; ++mf) {
        const int mrow = (int)mblk + wm*128 + mf*16 + quad*4;    // r=0 base
        const int b = mrow >> 9, s = mrow & 511;
        __bf16 pr[4];
#pragma unroll
        for (int r = 0; r < 4; ++r) pr[r] = f2bf(acc[mf][nf][r] + bval);
        *(bf16x4*)(vtout + (size_t)((b*H_ + h)*64 + d)*S_ + s) = *(bf16x4*)pr;
      }
    }
    return;
  }
  const float* bias = bq;
  if (SPLITV) bias = (blockIdx.x < 4) ? bq : bk;
  float bval[3]; int ncol[3];
#pragma unroll
  for (int nf = 0; nf < 3; ++nf) {
    ncol[nf] = (int)nblk + wn*48 + nf*16 + l16;
    int bc = ncol[nf]; if (bc >= 768) bc -= 768;
    bval[nf] = bias[bc];
  }
#pragma unroll
  for (int mf = 0; mf < 8; ++mf) {
#pragma unroll
    for (int nf = 0; nf < 3; ++nf) {
#pragma unroll
      for (int r = 0; r < 4; ++r) {
        const int mrow = (int)mblk + wm*128 + mf*16 + quad*4 + r;
        outb[(size_t)mrow*Nw + ncol[nf]] = f2bf(acc[mf][nf][r] + bval[nf]);
      }
    }
  }
}

// ---------------- flash attention v3: T14 async-stage + raw barriers + setprio ----------------
// R9 rewrite of the kv-tile pipeline. Old: __syncthreads / load->LDS / __syncthreads per kt
// -- __syncthreads drains vmcnt(0), so K/V HBM/L2 latency was fully exposed 8x per block.
// New: K/V for kt+1 are loaded into REGISTERS during kt's compute (issue-to-use distance =
// one full compute phase), written to LDS after the next barrier. Barriers are raw
// s_barrier + lgkmcnt(0)-only (prefetch loads stay in flight across them -- the T4
// mechanism applied to attention). sched_barrier(0) after each barrier (rule #18).
// sacc scaled in place (-16 VGPR) to offset the +24 VGPR prefetch cost; T5 setprio
// around both MFMA clusters (attn-proven +4-7%).
// 1-D grid of 3072: n&7 selects XCD-slot; bh = (n>>6)*8 + (n&7); qtile = (n>>3)&7.
#define PSTR 72   // padded LDS row stride (bf16): 144 B -> bank-even b128 access
__global__ __launch_bounds__(256) void flash_kernel(const __bf16* __restrict__ qkv,
                                                    const __bf16* __restrict__ vt,
                                                    __bf16* __restrict__ ctx) {
  __shared__ __align__(16) __bf16 Qs[64*PSTR];    // [q][d]
  __shared__ __align__(16) __bf16 Ks[64*PSTR];    // [kv][d]
  __shared__ __align__(16) __bf16 Vts[64*PSTR];   // [d][kv]
  __shared__ __align__(16) __bf16 Ps[64*PSTR];    // [q][kv], wave w owns rows w*16..+15
  const int tid = threadIdx.x;
  const int w = tid >> 6, lane = tid & 63;
  const int quad = lane >> 4, l16 = lane & 15;
  const int n = blockIdx.x;
  const int bh = (n >> 6)*8 + (n & 7);
  const int q0 = ((n >> 3) & 7) * 64;
  const int b = bh / H_, h = bh % H_;
  const float SCL = 0.125f * 1.44269504f;  // 1/sqrt(64) * log2(e)

  // per-thread staging slot (row, seg) for K/V tiles: 2 slots x 16 B
  const int row0 = tid >> 3,        seg0 = tid & 7;         // it=0
  const int row1 = (256 + tid) >> 3, seg1 = tid & 7;        // it=1 (rows 32..63)

  // ---- prologue: issue K/V loads for kt=0 (in flight during Q staging)
  bf16x8 ka[2], va[2], kb[2], vb[2];
  ka[0] = *(const bf16x8*)(qkv + (size_t)(b*S_ + row0)*2304 + 768 + h*64 + seg0*8);
  va[0] = *(const bf16x8*)(vt  + (size_t)(bh*64 + row0)*S_ + seg0*8);
  ka[1] = *(const bf16x8*)(qkv + (size_t)(b*S_ + row1)*2304 + 768 + h*64 + seg1*8);
  va[1] = *(const bf16x8*)(vt  + (size_t)(bh*64 + row1)*S_ + seg1*8);

  // ---- Q staging (once)
  {
    bf16x8 v0 = *(const bf16x8*)(qkv + (size_t)(b*S_ + q0 + row0)*2304 + h*64 + seg0*8);
    bf16x8 v1 = *(const bf16x8*)(qkv + (size_t)(b*S_ + q0 + row1)*2304 + h*64 + seg1*8);
    *(bf16x8*)&Qs[row0*PSTR + seg0*8] = v0;
    *(bf16x8*)&Qs[row1*PSTR + seg1*8] = v1;
  }

  floatx4 acc_o[4];   // C[m=q_local=quad*4+r][n=d=jd*16+l16]
#pragma unroll
  for (int jd = 0; jd < 4; ++jd) acc_o[jd] = {0.f,0.f,0.f,0.f};
  float m_prev = -__builtin_inff();   // per-lane q = w*16 + l16 (log2 domain)
  float l_part = 0.f;                 // per-quad partial of the softmax denom

  auto STEP = [&](int kt, bf16x8* ck, bf16x8* cv, bf16x8* nk, bf16x8* nv, bool pf) {
    // barrier #1: previous tile's Ks/Vts reads are consumed (lgkm drained per-wave)
    asm volatile("s_waitcnt lgkmcnt(0)" ::: "memory");
    __builtin_amdgcn_s_barrier();
    __builtin_amdgcn_sched_barrier(0);
    // write current K/V regs -> LDS (compiler inserts the vmcnt wait on their loads,
    // issued one full compute phase ago)
    *(bf16x8*)&Ks[row0*PSTR + seg0*8]  = ck[0];
    *(bf16x8*)&Vts[row0*PSTR + seg0*8] = cv[0];
    *(bf16x8*)&Ks[row1*PSTR + seg1*8]  = ck[1];
    *(bf16x8*)&Vts[row1*PSTR + seg1*8] = cv[1];
    // prefetch next tile into regs (issue only; consumed next STEP)
    if (pf) {
      nk[0] = *(const bf16x8*)(qkv + (size_t)(b*S_ + (kt+1)*64 + row0)*2304 + 768 + h*64 + seg0*8);
      nv[0] = *(const bf16x8*)(vt  + (size_t)(bh*64 + row0)*S_ + (kt+1)*64 + seg0*8);
      nk[1] = *(const bf16x8*)(qkv + (size_t)(b*S_ + (kt+1)*64 + row1)*2304 + 768 + h*64 + seg1*8);
      nv[1] = *(const bf16x8*)(vt  + (size_t)(bh*64 + row1)*S_ + (kt+1)*64 + seg1*8);
    }
    // barrier #2: ds_writes visible to all waves; prefetch loads REMAIN in flight
    asm volatile("s_waitcnt lgkmcnt(0)" ::: "memory");
    __builtin_amdgcn_s_barrier();
    __builtin_amdgcn_sched_barrier(0);

    // S^T tile: mfma(A=K, B=Q) -> C[m=kv=i*16+quad*4+r][n=q=w*16+l16]
    floatx4 sacc[4];
#pragma unroll
    for (int i = 0; i < 4; ++i) sacc[i] = {0.f,0.f,0.f,0.f};
    __builtin_amdgcn_s_setprio(1);
#pragma unroll
    for (int kk = 0; kk < 64; kk += 32) {
      bf16x8 bq_ = *(const bf16x8*)&Qs[(w*16 + l16)*PSTR + kk + quad*8];
#pragma unroll
      for (int i = 0; i < 4; ++i) {
        bf16x8 ak = *(const bf16x8*)&Ks[(i*16 + l16)*PSTR + kk + quad*8];
        sacc[i] = __builtin_amdgcn_mfma_f32_16x16x32_bf16(ak, bq_, sacc[i], 0, 0, 0);
      }
    }
    __builtin_amdgcn_s_setprio(0);
    // softmax (log2 domain), sacc scaled in place
#pragma unroll
    for (int i = 0; i < 4; ++i)
#pragma unroll
      for (int r = 0; r < 4; ++r) sacc[i][r] *= SCL;
    float mloc = sacc[0][0];
#pragma unroll
    for (int i = 0; i < 4; ++i)
#pragma unroll
      for (int r = 0; r < 4; ++r) mloc = fmaxf(mloc, sacc[i][r]);
    mloc = fmaxf(mloc, __shfl_xor(mloc, 16));
    mloc = fmaxf(mloc, __shfl_xor(mloc, 32));
    float mnew = fmaxf(m_prev, mloc);
    float alpha = fexp2(m_prev - mnew);
    m_prev = mnew;
    float rsum = 0.f;
#pragma unroll
    for (int i = 0; i < 4; ++i) {
      __bf16 pr[4];
#pragma unroll
      for (int r = 0; r < 4; ++r) {
        float p = fexp2(sacc[i][r] - mnew);
        rsum += p;
        pr[r] = f2bf(p);
      }
      *(bf16x4*)&Ps[(w*16 + l16)*PSTR + i*16 + quad*4] = *(bf16x4*)pr;  // b64, bank-even
    }
    l_part = l_part*alpha + rsum;
    float ab[4];
#pragma unroll
    for (int r = 0; r < 4; ++r) ab[r] = __shfl(alpha, quad*4 + r);
#pragma unroll
    for (int jd = 0; jd < 4; ++jd)
#pragma unroll
      for (int r = 0; r < 4; ++r) acc_o[jd][r] *= ab[r];
    // O += P V : same-wave ds write->read is in-order
#pragma unroll
    for (int kk = 0; kk < 64; kk += 32) {
      bf16x8 ap = *(const bf16x8*)&Ps[(w*16 + l16)*PSTR + kk + quad*8];
      __builtin_amdgcn_s_setprio(1);
#pragma unroll
      for (int jd = 0; jd < 4; ++jd) {
        bf16x8 bv_ = *(const bf16x8*)&Vts[(jd*16 + l16)*PSTR + kk + quad*8];
        acc_o[jd] = __builtin_amdgcn_mfma_f32_16x16x32_bf16(ap, bv_, acc_o[jd], 0, 0, 0);
      }
      __builtin_amdgcn_s_setprio(0);
    }
  };

#pragma unroll
  for (int kt2 = 0; kt2 < 8; kt2 += 2) {
    STEP(kt2,     ka, va, kb, vb, true);
    STEP(kt2 + 1, kb, vb, ka, va, kt2 + 1 < 7);
  }

  float l_tot = l_part;
  l_tot += __shfl_xor(l_tot, 16);
  l_tot += __shfl_xor(l_tot, 32);
  float lb[4];
#pragma unroll
  for (int r = 0; r < 4; ++r) lb[r] = __shfl(l_tot, quad*4 + r);
#pragma unroll
  for (int jd = 0; jd < 4; ++jd) {
    const int d = jd*16 + l16;
#pragma unroll
    for (int r = 0; r < 4; ++r) {
      const int q = q0 + w*16 + quad*4 + r;
      ctx[(size_t)(b*S_ + q)*D_ + h*64 + d] = f2bf(acc_o[jd][r] / lb[r]);
    }
  }
}

// ---------------- residual + LayerNorm v2: wave-per-row, bf16 master chain ----------------
// 4 rows/block (one wave each), bf16x8 loads, shuffle-only reduction (no LDS/barrier).
// Lane covers cols lane*8..+7 (all lanes) and 512+lane*8..+7 (lanes<32).
// FIRST: residual read from fp32 hidden. LAST: write fp32 to d_out; else bf16 in-place xb.
template<bool FIRST, bool LAST>
__global__ __launch_bounds__(256) void ln_kernel(const float* __restrict__ residf,
                                                 __bf16* xb,           // resid in (l>0) + out (l<11); in-place
                                                 const __bf16* __restrict__ proj,
                                                 const float* __restrict__ gamma,
                                                 const float* __restrict__ beta,
                                                 float* __restrict__ xoutf) {
  const int tid = threadIdx.x;
  const int w = tid >> 6, lane = tid & 63;
  const int row = blockIdx.x*4 + w;
  const size_t base = (size_t)row * D_;
  const int c0 = lane*8;
  const bool has2 = lane < 32;
  const int c1 = 512 + lane*8;

  float v0[8], v1[8];
  {
    bf16x8 p0 = *(const bf16x8*)(proj + base + c0);
    if (FIRST) {
      float4 a = *(const float4*)(residf + base + c0);
      float4 bq4 = *(const float4*)(residf + base + c0 + 4);
      v0[0]=a.x+(float)p0[0]; v0[1]=a.y+(float)p0[1]; v0[2]=a.z+(float)p0[2]; v0[3]=a.w+(float)p0[3];
      v0[4]=bq4.x+(float)p0[4]; v0[5]=bq4.y+(float)p0[5]; v0[6]=bq4.z+(float)p0[6]; v0[7]=bq4.w+(float)p0[7];
    } else {
      bf16x8 r0 = *(const bf16x8*)(xb + base + c0);
#pragma unroll
      for (int j = 0; j < 8; ++j) v0[j] = (float)r0[j] + (float)p0[j];
    }
    if (has2) {
      bf16x8 p1 = *(const bf16x8*)(proj + base + c1);
      if (FIRST) {
        float4 a = *(const float4*)(residf + base + c1);
        float4 bq4 = *(const float4*)(residf + base + c1 + 4);
        v1[0]=a.x+(float)p1[0]; v1[1]=a.y+(float)p1[1]; v1[2]=a.z+(float)p1[2]; v1[3]=a.w+(float)p1[3];
        v1[4]=bq4.x+(float)p1[4]; v1[5]=bq4.y+(float)p1[5]; v1[6]=bq4.z+(float)p1[6]; v1[7]=bq4.w+(float)p1[7];
      } else {
        bf16x8 r1 = *(const bf16x8*)(xb + base + c1);
#pragma unroll
        for (int j = 0; j < 8; ++j) v1[j] = (float)r1[j] + (float)p1[j];
      }
    } else {
#pragma unroll
      for (int j = 0; j < 8; ++j) v1[j] = 0.f;
    }
  }
  float s = 0.f;
#pragma unroll
  for (int j = 0; j < 8; ++j) s += v0[j] + v1[j];
#pragma unroll
  for (int off = 32; off; off >>= 1) s += __shfl_xor(s, off);
  const float mu = s * (1.f/768.f);
  float q = 0.f;
#pragma unroll
  for (int j = 0; j < 8; ++j) { float d0 = v0[j]-mu; q += d0*d0; }
  if (has2) {
#pragma unroll
    for (int j = 0; j < 8; ++j) { float d1 = v1[j]-mu; q += d1*d1; }
  }
#pragma unroll
  for (int off = 32; off; off >>= 1) q += __shfl_xor(q, off);
  const float rs = rsqrtf(q * (1.f/768.f) + 1e-12f);

  {
    float4 g0 = *(const float4*)(gamma + c0);
    float4 g1 = *(const float4*)(gamma + c0 + 4);
    float4 b0 = *(const float4*)(beta + c0);
    float4 b1 = *(const float4*)(beta + c0 + 4);
    float o[8];
    o[0]=(v0[0]-mu)*rs*g0.x+b0.x; o[1]=(v0[1]-mu)*rs*g0.y+b0.y;
    o[2]=(v0[2]-mu)*rs*g0.z+b0.z; o[3]=(v0[3]-mu)*rs*g0.w+b0.w;
    o[4]=(v0[4]-mu)*rs*g1.x+b1.x; o[5]=(v0[5]-mu)*rs*g1.y+b1.y;
    o[6]=(v0[6]-mu)*rs*g1.z+b1.z; o[7]=(v0[7]-mu)*rs*g1.w+b1.w;
    if (LAST) {
      *(float4*)(xoutf + base + c0)     = {o[0],o[1],o[2],o[3]};
      *(float4*)(xoutf + base + c0 + 4) = {o[4],o[5],o[6],o[7]};
    } else {
      __bf16 ob[8];
#pragma unroll
      for (int j = 0; j < 8; ++j) ob[j] = f2bf(o[j]);
      *(bf16x8*)(xb + base + c0) = *(bf16x8*)ob;
    }
  }
  if (has2) {
    float4 g0 = *(const float4*)(gamma + c1);
    float4 g1 = *(const float4*)(gamma + c1 + 4);
    float4 b0 = *(const float4*)(beta + c1);
    float4 b1 = *(const float4*)(beta + c1 + 4);
    float o[8];
    o[0]=(v1[0]-mu)*rs*g0.x+b0.x; o[1]=(v1[1]-mu)*rs*g0.y+b0.y;
    o[2]=(v1[2]-mu)*rs*g0.z+b0.z; o[3]=(v1[3]-mu)*rs*g0.w+b0.w;
    o[4]=(v1[4]-mu)*rs*g1.x+b1.x; o[5]=(v1[5]-mu)*rs*g1.y+b1.y;
    o[6]=(v1[6]-mu)*rs*g1.z+b1.z; o[7]=(v1[7]-mu)*rs*g1.w+b1.w;
    if (LAST) {
      *(float4*)(xoutf + base + c1)     = {o[0],o[1],o[2],o[3]};
      *(float4*)(xoutf + base + c1 + 4) = {o[4],o[5],o[6],o[7]};
    } else {
      __bf16 ob[8];
#pragma unroll
      for (int j = 0; j < 8; ++j) ob[j] = f2bf(o[j]);
      *(bf16x8*)(xb + base + c1) = *(bf16x8*)ob;
    }
  }
}

extern "C" void kernel_launch(void* const* d_in, const int* in_sizes, int n_in,
                              void* d_out, int out_size, void* d_ws, size_t ws_size,
                              hipStream_t stream) {
  const float* hidden = (const float*)d_in[0];
  const float* router = (const float*)d_in[1];
  const float* qc[6]; const float* vc[6];
  for (int i = 0; i < 6; ++i) qc[i] = (const float*)d_in[2+i];
  for (int i = 0; i < 6; ++i) vc[i] = (const float*)d_in[8+i];
  const float* Wq = (const float*)d_in[14];
  const float* Wk = (const float*)d_in[15];
  const float* Wv = (const float*)d_in[16];
  const float* Wo = (const float*)d_in[17];
  const float* bq = (const float*)d_in[18];
  const float* bk = (const float*)d_in[19];
  const float* bv = (const float*)d_in[20];
  const float* bo = (const float*)d_in[21];
  const float* lns = (const float*)d_in[22];
  const float* lnb = (const float*)d_in[23];
  float* out = (float*)d_out;

  char* ws = (char*)d_ws;
  size_t off = 0;
  auto alloc = [&](size_t bytes) -> void* {
    off = (off + 255) & ~(size_t)255;
    void* p = ws + off; off += bytes; return p;
  };
  int*    e_idx = (int*)   alloc(4);
  float*  rpart = (float*) alloc((size_t)64*D_*4);
  __bf16* xbf   = (__bf16*)alloc((size_t)BS_*D_*2);
  __bf16* qkv   = (__bf16*)alloc((size_t)BS_*2304*2);
  __bf16* vt    = (__bf16*)alloc((size_t)B_*H_*64*S_*2);
  __bf16* ctx   = (__bf16*)alloc((size_t)BS_*D_*2);
  __bf16* projb = (__bf16*)alloc((size_t)BS_*D_*2);
  __bf16* wqkv  = (__bf16*)alloc((size_t)L_*2304*D_*2);
  __bf16* wobf  = (__bf16*)alloc((size_t)L_*D_*D_*2);
  (void)ws_size; (void)in_sizes; (void)n_in; (void)out_size;

  routing_pool_kernel<<<64, 256, 0, stream>>>(hidden, rpart);
  routing_finish_kernel<<<1, 256, 0, stream>>>(rpart, router, e_idx);
  convert_bf16_kernel<<<(BS_*D_)/2048, 256, 0, stream>>>(hidden, xbf);
  tt_prep_kernel<<<dim3(L_, 2, 16), 256, 0, stream>>>(qc[0],qc[1],qc[2],qc[3],qc[4],qc[5],
                                                      vc[0],vc[1],vc[2],vc[3],vc[4],vc[5],
                                                      Wq, Wv, e_idx, wqkv);
  convert_wk_kernel<<<(L_*D_*D_)/2048, 256, 0, stream>>>(Wk, wqkv);
  convert_bf16_kernel<<<(L_*D_*D_)/2048, 256, 0, stream>>>(Wo, wobf);

  for (int l = 0; l < L_; ++l) {
    gemm_bt<true><<<dim3(12,64), 512, 0, stream>>>(xbf, wqkv + (size_t)l*2304*D_,
        bq + l*D_, bk + l*D_, bv + l*D_, qkv, vt, 2304);
    flash_kernel<<<3072, 256, 0, stream>>>(qkv, vt, ctx);
    gemm_bt<false><<<dim3(4,64), 512, 0, stream>>>(ctx, wobf + (size_t)l*D_*D_,
        bo + l*D_, nullptr, nullptr, projb, nullptr, 768);
    if (l == 0)
      ln_kernel<true,false><<<BS_/4, 256, 0, stream>>>(hidden, xbf, projb,
          lns + l*D_, lnb + l*D_, nullptr);
    else if (l == L_-1)
      ln_kernel<false,true><<<BS_/4, 256, 0, stream>>>(nullptr, xbf, projb,
          lns + l*D_, lnb + l*D_, out);
    else
      ln_kernel<false,false><<<BS_/4, 256, 0, stream>>>(nullptr, xbf, projb,
          lns + l*D_, lnb + l*D_, nullptr);
  }
}

// Round 5
// 2253.930 us; speedup vs baseline: 1.1744x; 1.0853x over previous
//
#include <hip/hip_runtime.h>
#include <hip/hip_bf16.h>
#include <stdint.h>

#define E_ 8
#define L_ 12
#define D_ 768
#define H_ 12
#define S_ 512
#define B_ 32
#define BS_ (B_*S_)   // 16384

typedef __attribute__((ext_vector_type(4))) float floatx4;
typedef __attribute__((ext_vector_type(8))) __bf16 bf16x8;
typedef __attribute__((ext_vector_type(4))) __bf16 bf16x4;
typedef __attribute__((ext_vector_type(2))) unsigned uintx2;

__device__ __forceinline__ __bf16 f2bf(float f) {
  unsigned u = __builtin_bit_cast(unsigned, f);
  u += 0x7fffu + ((u >> 16) & 1u);           // RNE
  unsigned short h = (unsigned short)(u >> 16);
  return __builtin_bit_cast(__bf16, h);
}

// HW packed f32x2 -> bf16x2 (RNE). Strict win over 2x manual f2bf (4 VALU each).
__device__ __forceinline__ unsigned cvtpk_bf16(float lo, float hi) {
  unsigned r;
  asm("v_cvt_pk_bf16_f32 %0, %1, %2" : "=v"(r) : "v"(lo), "v"(hi));
  return r;
}

__device__ __forceinline__ float fexp2(float x) {
#if __has_builtin(__builtin_amdgcn_exp2f)
  return __builtin_amdgcn_exp2f(x);
#else
  return exp2f(x);
#endif
}

__device__ __forceinline__ void async16(const void* g, void* l) {
  __builtin_amdgcn_global_load_lds((__attribute__((address_space(1))) void*)g,
                                   (__attribute__((address_space(3))) void*)l,
                                   16, 0, 0);
}

// ---------------- routing stage 1: 64 blocks x 8 rows, coalesced partial sums ----------------
__global__ void routing_pool_kernel(const float* __restrict__ hidden,
                                    float* __restrict__ partial) {
  const int blk = blockIdx.x;    // 0..63
  const int tid = threadIdx.x;
  const float* base = hidden + (size_t)(B_-1)*S_*D_ + (size_t)blk*8*D_;
  float acc[3] = {0.f, 0.f, 0.f};
  for (int s = 0; s < 8; ++s) {
#pragma unroll
    for (int i = 0; i < 3; ++i)
      acc[i] += base[(size_t)s*D_ + tid + i*256];
  }
#pragma unroll
  for (int i = 0; i < 3; ++i) partial[(size_t)blk*D_ + tid + i*256] = acc[i];
}

// ---------------- routing stage 2: reduce partials, logits, argmax ----------------
__global__ void routing_finish_kernel(const float* __restrict__ partial,
                                      const float* __restrict__ rw,
                                      int* __restrict__ e_out) {
  __shared__ float pooled[D_];
  __shared__ float logits[E_];
  int tid = threadIdx.x;
#pragma unroll
  for (int i = 0; i < 3; ++i) {
    int d = tid + i*256;
    float s = 0.f;
    for (int blk = 0; blk < 64; ++blk) s += partial[(size_t)blk*D_ + d];
    pooled[d] = s;  // positive scale factor irrelevant for argmax
  }
  __syncthreads();
  if (tid < E_) {
    float s = 0.f;
    for (int d = 0; d < D_; ++d) s += pooled[d] * rw[d*E_ + tid];
    logits[tid] = s;
  }
  __syncthreads();
  if (tid == 0) {
    int best = 0; float bvv = logits[0];
    for (int e = 1; e < E_; ++e) if (logits[e] > bvv) { bvv = logits[e]; best = e; }
    e_out[0] = best;
  }
}

// ---------------- fp32 -> bf16 convert (n multiple of 2048) ----------------
__global__ void convert_bf16_kernel(const float* __restrict__ src, __bf16* __restrict__ dst) {
  size_t i = ((size_t)blockIdx.x*256 + threadIdx.x)*8;
  __bf16 r[8];
#pragma unroll
  for (int j = 0; j < 8; ++j) r[j] = f2bf(src[i+j]);
  *(bf16x8*)(dst + i) = *(bf16x8*)r;
}

// Wk [L][768][768] fp32 -> rows 768..1535 of wqkv [L][2304][768] bf16
__global__ void convert_wk_kernel(const float* __restrict__ wk, __bf16* __restrict__ wqkv) {
  size_t i = ((size_t)blockIdx.x*256 + threadIdx.x)*8;
  int l = (int)(i / (D_*D_));
  int rem = (int)(i % (D_*D_));
  int n = rem / D_, k = rem % D_;
  __bf16 r[8];
#pragma unroll
  for (int j = 0; j < 8; ++j) r[j] = f2bf(wk[i+j]);
  *(bf16x8*)(wqkv + (size_t)l*2304*D_ + (size_t)(768+n)*D_ + k) = *(bf16x8*)r;
}

// ---------------- TT adapter build: Wq_a / Wv_a -> wqkv bf16 ----------------
__global__ void tt_prep_kernel(
    const float* __restrict__ qc0, const float* __restrict__ qc1, const float* __restrict__ qc2,
    const float* __restrict__ qc3, const float* __restrict__ qc4, const float* __restrict__ qc5,
    const float* __restrict__ vc0, const float* __restrict__ vc1, const float* __restrict__ vc2,
    const float* __restrict__ vc3, const float* __restrict__ vc4, const float* __restrict__ vc5,
    const float* __restrict__ Wq, const float* __restrict__ Wv,
    const int* __restrict__ e_idx, __bf16* __restrict__ wqkv) {
  const int l = blockIdx.x;
  const int pre = blockIdx.y;         // 0 = q, 1 = v
  const int z = blockIdx.z;           // 0..15 -> rows 48z..48z+47
  const int tid = threadIdx.x;
  const int e = e_idx[0];
  const float* c0 = (pre ? vc0 : qc0) + (size_t)(e*L_ + l)*96;   // [12][8]
  const float* c1 = (pre ? vc1 : qc1) + (size_t)(e*L_ + l)*512;  // [8][8][8]
  const float* c2 = (pre ? vc2 : qc2) + (size_t)(e*L_ + l)*512;
  const float* c3 = (pre ? vc3 : qc3) + (size_t)(e*L_ + l)*512;
  const float* c4 = (pre ? vc4 : qc4) + (size_t)(e*L_ + l)*512;
  const float* c5 = (pre ? vc5 : qc5) + (size_t)(e*L_ + l)*96;   // [8][12]
  __shared__ float M1[768];   // [j][l2][m]
  __shared__ float R2[768];   // [q][r][t]
  __shared__ float M2[6144];  // [out][o]
  __shared__ float Rm[6144];  // [o][in]
  for (int idx = tid; idx < 768; idx += 256) {
    int j = idx >> 6, rem = idx & 63, l2 = rem >> 3, m = rem & 7;
    float s = 0.f;
    for (int k = 0; k < 8; ++k) s += c0[j*8 + k] * c1[k*64 + l2*8 + m];
    M1[idx] = s;
    int qq = idx / 96, rem2 = idx % 96, rr = rem2 / 12, t = rem2 % 12;
    float s2 = 0.f;
    for (int si = 0; si < 8; ++si) s2 += c4[qq*64 + rr*8 + si] * c5[si*12 + t];
    R2[idx] = s2;
  }
  __syncthreads();
  for (int idx = tid; idx < 6144; idx += 256) {
    int o = idx & 7, n = (idx >> 3) & 7, jl = idx >> 6;
    float s = 0.f;
    for (int m = 0; m < 8; ++m) s += M1[jl*8 + m] * c2[m*64 + n*8 + o];
    M2[idx] = s;
    int o2 = idx / 768, inp = idx % 768, p = inp / 96, rt = inp % 96;
    float s2 = 0.f;
    for (int qq = 0; qq < 8; ++qq) s2 += c3[o2*64 + p*8 + qq] * R2[qq*96 + rt];
    Rm[idx] = s2;
  }
  __syncthreads();
  const float* Wbase = (pre ? Wv : Wq) + (size_t)l*D_*D_;
  __bf16* dst = wqkv + (size_t)l*2304*D_ + (pre ? (size_t)1536*D_ : 0);
  for (int g = tid; g < 48*96; g += 256) {
    const int outr = z*48 + (g / 96);
    const int inp0 = (g % 96) * 8;
    float m2r[8];
#pragma unroll
    for (int o = 0; o < 8; ++o) m2r[o] = M2[outr*8 + o];
    float acc[8];
#pragma unroll
    for (int u = 0; u < 8; ++u) acc[u] = 0.f;
#pragma unroll
    for (int o = 0; o < 8; ++o) {
      float4 r0 = *(const float4*)&Rm[o*768 + inp0];
      float4 r1 = *(const float4*)&Rm[o*768 + inp0 + 4];
      acc[0] += m2r[o]*r0.x; acc[1] += m2r[o]*r0.y;
      acc[2] += m2r[o]*r0.z; acc[3] += m2r[o]*r0.w;
      acc[4] += m2r[o]*r1.x; acc[5] += m2r[o]*r1.y;
      acc[6] += m2r[o]*r1.z; acc[7] += m2r[o]*r1.w;
    }
    const float* wb = Wbase + (size_t)outr*768 + inp0;
    float4 w0 = *(const float4*)wb;
    float4 w1 = *(const float4*)(wb + 4);
    __bf16 r[8];
    r[0] = f2bf(w0.x + 8.f*acc[0]); r[1] = f2bf(w0.y + 8.f*acc[1]);
    r[2] = f2bf(w0.z + 8.f*acc[2]); r[3] = f2bf(w0.w + 8.f*acc[3]);
    r[4] = f2bf(w1.x + 8.f*acc[4]); r[5] = f2bf(w1.y + 8.f*acc[5]);
    r[6] = f2bf(w1.z + 8.f*acc[6]); r[7] = f2bf(w1.w + 8.f*acc[7]);
    *(bf16x8*)(dst + (size_t)outr*768 + inp0) = *(bf16x8*)r;
  }
}

// ---------------- bf16 MFMA GEMM v3 (R7-proven best): 256x192, BK=32, ring-4, split clusters ----------------
// Reverted/locked since R9 (79 us QKV). R8's 256x256 ring-2 regressed (96.7 us):
// bad grid quantization + vmcnt(0) full-drain killed the depth-3 prefetch. Keep: ring-4
// slots, prefetch distance 3, counted vmcnt (never 0 in main loop), T2 line-XOR swizzle
// (bank conflicts = 0), split 12-MFMA clusters, T5 setprio.
// Grid: QKV (12,64) = 768 blocks = exactly 3 CU rounds; proj (4,64) = 1 round.
#define SLOT_BYTES 28672
template<bool SPLITV>
__global__ __launch_bounds__(512, 2) void gemm_bt(
    const __bf16* __restrict__ A, const __bf16* __restrict__ Bw,
    const float* __restrict__ bq, const float* __restrict__ bk, const float* __restrict__ bvp,
    __bf16* __restrict__ outb, __bf16* __restrict__ vtout, int Nw) {
  __shared__ __align__(16) char lds[4*SLOT_BYTES];   // 112 KiB
  const int tid = threadIdx.x;
  const int w = tid >> 6, lane = tid & 63;
  const int quad = lane >> 4, l16 = lane & 15;
  const int wm = w >> 2, wn = w & 3;
  const size_t mblk = (size_t)blockIdx.y * 256;
  const size_t nblk = (size_t)blockIdx.x * 192;
  const __bf16* Ag = A + mblk * 768;
  const __bf16* Bg = Bw + nblk * 768;

  // ---- staging descriptors: per-lane pre-swizzled global offsets, wave-uniform LDS bases
  int a_goff[2], a_loff[2];
#pragma unroll
  for (int i = 0; i < 2; ++i) {
    int line = w*16 + i*8 + (lane >> 3);          // A line 0..127
    int s8 = (lane & 7) ^ (line & 7);
    int row = 2*line + (s8 >> 2);                 // logical A row 0..255
    a_goff[i] = row*768 + (s8 & 3)*8;             // elements
    a_loff[i] = (w*16 + i*8)*128;                 // bytes; HW appends lane*16
  }
  int b_goff[2], b_loff[2];
#pragma unroll
  for (int i = 0; i < 2; ++i) {
    int bl0 = (w < 4) ? (w*16 + i*8) : (64 + (w-4)*8);   // B line base (0..95)
    int line = bl0 + (lane >> 3);
    int s8 = (lane & 7) ^ (line & 7);
    int row = 2*line + (s8 >> 2);                 // logical B row 0..191
    b_goff[i] = row*768 + (s8 & 3)*8;
    b_loff[i] = 16384 + bl0*128;                  // B region starts at 16 KiB
  }

  // ---- fragment ds_read byte offsets (swizzled; 2-way max bank aliasing)
  int a_foff[8], b_foff[3];
#pragma unroll
  for (int mf = 0; mf < 8; ++mf) {
    int r = wm*128 + mf*16 + l16;
    int line = r >> 1, s8 = (r & 1)*4 + quad, ph = s8 ^ (line & 7);
    a_foff[mf] = line*128 + ph*16;
  }
#pragma unroll
  for (int nf = 0; nf < 3; ++nf) {
    int r = wn*48 + nf*16 + l16;
    int line = r >> 1, s8 = (r & 1)*4 + quad, ph = s8 ^ (line & 7);
    b_foff[nf] = 16384 + line*128 + ph*16;
  }

  floatx4 acc[8][3];
#pragma unroll
  for (int mf = 0; mf < 8; ++mf)
#pragma unroll
    for (int nf = 0; nf < 3; ++nf) acc[mf][nf] = {0.f,0.f,0.f,0.f};

  auto STAGE = [&](int t) {
    const __bf16* Ab = Ag + t*32;
    const __bf16* Bb = Bg + t*32;
    char* ls = lds + (t & 3)*SLOT_BYTES;
    async16(Ab + a_goff[0], ls + a_loff[0]);
    async16(Ab + a_goff[1], ls + a_loff[1]);
    if (w < 4) {
      async16(Bb + b_goff[0], ls + b_loff[0]);
      async16(Bb + b_goff[1], ls + b_loff[1]);
    } else {
      async16(Bb + b_goff[0], ls + b_loff[0]);
    }
  };

  bf16x8 af[8], bfr[3];
  auto LOAD1 = [&](int u) {
    const char* ls = lds + (u & 3)*SLOT_BYTES;
#pragma unroll
    for (int nf = 0; nf < 3; ++nf) bfr[nf] = *(const bf16x8*)(ls + b_foff[nf]);
#pragma unroll
    for (int mf = 0; mf < 4; ++mf) af[mf] = *(const bf16x8*)(ls + a_foff[mf]);
  };
  auto LOAD2 = [&](int u) {
    const char* ls = lds + (u & 3)*SLOT_BYTES;
#pragma unroll
    for (int mf = 4; mf < 8; ++mf) af[mf] = *(const bf16x8*)(ls + a_foff[mf]);
  };
  auto MM = [&](int mf0) {
    __builtin_amdgcn_s_setprio(1);
#pragma unroll
    for (int mf = mf0; mf < mf0 + 4; ++mf)
#pragma unroll
      for (int nf = 0; nf < 3; ++nf)
        acc[mf][nf] = __builtin_amdgcn_mfma_f32_16x16x32_bf16(af[mf], bfr[nf], acc[mf][nf], 0, 0, 0);
    __builtin_amdgcn_s_setprio(0);
  };
  auto BAR = [&]() {
    __builtin_amdgcn_s_barrier();
    __builtin_amdgcn_sched_barrier(0);
  };

  // ---- prologue: 3 subtiles in flight; validate subtile 0
  STAGE(0); STAGE(1); STAGE(2);
  if (w < 4) asm volatile("s_waitcnt vmcnt(8)" ::: "memory");
  else       asm volatile("s_waitcnt vmcnt(6)" ::: "memory");
  BAR();

  // ---- main loop: u = 0..20 (STAGE(u+3) valid, steady vmcnt)
  for (int u = 0; u < 21; ++u) {
    LOAD1(u);
    BAR();
    MM(0);
    LOAD2(u);
    STAGE(u + 3);
    if (w < 4) asm volatile("s_waitcnt vmcnt(8)" ::: "memory");
    else       asm volatile("s_waitcnt vmcnt(6)" ::: "memory");
    BAR();
    MM(4);
  }
  // ---- u = 21: no stage; validate 22
  LOAD1(21);
  BAR();
  MM(0);
  LOAD2(21);
  if (w < 4) asm volatile("s_waitcnt vmcnt(4)" ::: "memory");
  else       asm volatile("s_waitcnt vmcnt(3)" ::: "memory");
  BAR();
  MM(4);
  // ---- u = 22: validate 23
  LOAD1(22);
  BAR();
  MM(0);
  LOAD2(22);
  asm volatile("s_waitcnt vmcnt(0)" ::: "memory");
  BAR();
  MM(4);
  // ---- u = 23: final
  LOAD1(23);
  BAR();
  MM(0);
  LOAD2(23);
  BAR();
  MM(4);

  // ---- epilogue
  if (SPLITV && blockIdx.x >= 8) {
    // V region (cols 1536..2303): bias + transpose-write into vt[bh][64][512]
#pragma unroll
    for (int nf = 0; nf < 3; ++nf) {
      const int vcol = (int)nblk - 1536 + wn*48 + nf*16 + l16;   // 0..767
      const int h = vcol >> 6, d = vcol & 63;
      const float bval = bvp[vcol];
#pragma unroll
      for (int mf = 0; mf < 8; ++mf) {
        const int mrow = (int)mblk + wm*128 + mf*16 + quad*4;    // r=0 base
        const int b = mrow >> 9, s = mrow & 511;
        __bf16 pr[4];
#pragma unroll
        for (int r = 0; r < 4; ++r) pr[r] = f2bf(acc[mf][nf][r] + bval);
        *(bf16x4*)(vtout + (size_t)((b*H_ + h)*64 + d)*S_ + s) = *(bf16x4*)pr;
      }
    }
    return;
  }
  const float* bias = bq;
  if (SPLITV) bias = (blockIdx.x < 4) ? bq : bk;
  float bval[3]; int ncol[3];
#pragma unroll
  for (int nf = 0; nf < 3; ++nf) {
    ncol[nf] = (int)nblk + wn*48 + nf*16 + l16;
    int bc = ncol[nf]; if (bc >= 768) bc -= 768;
    bval[nf] = bias[bc];
  }
#pragma unroll
  for (int mf = 0; mf < 8; ++mf) {
#pragma unroll
    for (int nf = 0; nf < 3; ++nf) {
#pragma unroll
      for (int r = 0; r < 4; ++r) {
        const int mrow = (int)mblk + wm*128 + mf*16 + quad*4 + r;
        outb[(size_t)mrow*Nw + ncol[nf]] = f2bf(acc[mf][nf][r] + bval[nf]);
      }
    }
  }
}

// ---------------- flash attention v4: VALU-diet ----------------
// R10 (flash was #1 dispatch, 85 us, VALUBusy 48% / MfmaUtil 12% / HBM 9% -> VALU-bound):
//  - Q fragments hoisted to REGISTERS (loop-invariant per lane): Qs LDS buffer deleted
//    (-9.2 KB LDS, -2 b128 reads/step, -1 staging pass).
//  - P pack via v_cvt_pk_bf16_f32 (HW RNE): ~64 VALU/step -> 8.
//  - T13 defer-max (THR=10, log2 domain): skip O-rescale + alpha shfl when
//    __all(mloc <= m_prev+10) -- nearly always after tile 0. P bounded by 2^10 (bf16-safe).
//  - Prefetch via 4 persistent pointers bumped by constant strides (no 64-bit recompute).
//  - Epilogue: 4 reciprocals instead of 16 divides.
// Keeps R9's T14 pipeline: K/V kt+1 -> regs during kt compute; raw s_barrier +
// lgkmcnt(0)-only (prefetch stays in flight across barriers); sched_barrier(0) (rule #18).
#define PSTR 72   // padded LDS row stride (bf16): 144 B
__global__ __launch_bounds__(256, 4) void flash_kernel(const __bf16* __restrict__ qkv,
                                                       const __bf16* __restrict__ vt,
                                                       __bf16* __restrict__ ctx) {
  __shared__ __align__(16) __bf16 Ks[64*PSTR];    // [kv][d]
  __shared__ __align__(16) __bf16 Vts[64*PSTR];   // [d][kv]
  __shared__ __align__(16) __bf16 Ps[64*PSTR];    // [q][kv], wave w owns rows w*16..+15
  const int tid = threadIdx.x;
  const int w = tid >> 6, lane = tid & 63;
  const int quad = lane >> 4, l16 = lane & 15;
  const int n = blockIdx.x;
  const int bh = (n >> 6)*8 + (n & 7);
  const int q0 = ((n >> 3) & 7) * 64;
  const int b = bh / H_, h = bh % H_;
  const float SCL = 0.125f * 1.44269504f;  // 1/sqrt(64) * log2(e)

  // per-thread staging slot (row, seg) for K/V tiles: 2 slots x 16 B
  const int row0 = tid >> 3,         seg0 = tid & 7;        // rows 0..31
  const int row1 = (256 + tid) >> 3, seg1 = tid & 7;        // rows 32..63

  // ---- prologue: issue K/V loads for kt=0
  bf16x8 ka[2], va[2], kb[2], vb[2];
  ka[0] = *(const bf16x8*)(qkv + (size_t)(b*S_ + row0)*2304 + 768 + h*64 + seg0*8);
  va[0] = *(const bf16x8*)(vt  + (size_t)(bh*64 + row0)*S_ + seg0*8);
  ka[1] = *(const bf16x8*)(qkv + (size_t)(b*S_ + row1)*2304 + 768 + h*64 + seg1*8);
  va[1] = *(const bf16x8*)(vt  + (size_t)(bh*64 + row1)*S_ + seg1*8);

  // ---- Q fragments straight to registers (loop-invariant): row q0+w*16+l16,
  // d = kk + quad*8 .. +7 for kk = 0, 32 -- exactly the B-operand fragment layout.
  bf16x8 qf0, qf1;
  {
    const __bf16* qrow = qkv + (size_t)(b*S_ + q0 + w*16 + l16)*2304 + h*64 + quad*8;
    qf0 = *(const bf16x8*)qrow;
    qf1 = *(const bf16x8*)(qrow + 32);
  }

  // prefetch pointers (kt=1 bases), bumped by constant strides
  const __bf16* kp0 = qkv + (size_t)(b*S_ + 64 + row0)*2304 + 768 + h*64 + seg0*8;
  const __bf16* kp1 = qkv + (size_t)(b*S_ + 64 + row1)*2304 + 768 + h*64 + seg1*8;
  const __bf16* vp0 = vt  + (size_t)(bh*64 + row0)*S_ + 64 + seg0*8;
  const __bf16* vp1 = vt  + (size_t)(bh*64 + row1)*S_ + 64 + seg1*8;

  floatx4 acc_o[4];   // C[m=q_local=quad*4+r][n=d=jd*16+l16]
#pragma unroll
  for (int jd = 0; jd < 4; ++jd) acc_o[jd] = {0.f,0.f,0.f,0.f};
  float m_prev = -__builtin_inff();   // per-lane q = w*16 + l16 (log2 domain)
  float l_part = 0.f;                 // per-quad partial of the softmax denom

  auto STEP = [&](bf16x8* ck, bf16x8* cv, bf16x8* nk, bf16x8* nv, bool pf) {
    // barrier #1: previous tile's Ks/Vts reads are consumed (lgkm drained per-wave)
    asm volatile("s_waitcnt lgkmcnt(0)" ::: "memory");
    __builtin_amdgcn_s_barrier();
    __builtin_amdgcn_sched_barrier(0);
    // write current K/V regs -> LDS (compiler inserts the vmcnt wait on their loads,
    // issued one full compute phase ago)
    *(bf16x8*)&Ks[row0*PSTR + seg0*8]  = ck[0];
    *(bf16x8*)&Vts[row0*PSTR + seg0*8] = cv[0];
    *(bf16x8*)&Ks[row1*PSTR + seg1*8]  = ck[1];
    *(bf16x8*)&Vts[row1*PSTR + seg1*8] = cv[1];
    // prefetch next tile into regs (issue only; consumed next STEP)
    if (pf) {
      nk[0] = *(const bf16x8*)kp0; kp0 += 64*2304;
      nv[0] = *(const bf16x8*)vp0; vp0 += 64;
      nk[1] = *(const bf16x8*)kp1; kp1 += 64*2304;
      nv[1] = *(const bf16x8*)vp1; vp1 += 64;
    }
    // barrier #2: ds_writes visible; prefetch loads REMAIN in flight
    asm volatile("s_waitcnt lgkmcnt(0)" ::: "memory");
    __builtin_amdgcn_s_barrier();
    __builtin_amdgcn_sched_barrier(0);

    // S^T tile: mfma(A=K, B=Q) -> C[m=kv=i*16+quad*4+r][n=q=w*16+l16]
    floatx4 sacc[4];
#pragma unroll
    for (int i = 0; i < 4; ++i) sacc[i] = {0.f,0.f,0.f,0.f};
    __builtin_amdgcn_s_setprio(1);
#pragma unroll
    for (int kk = 0; kk < 64; kk += 32) {
      bf16x8 bq_ = kk ? qf1 : qf0;
#pragma unroll
      for (int i = 0; i < 4; ++i) {
        bf16x8 ak = *(const bf16x8*)&Ks[(i*16 + l16)*PSTR + kk + quad*8];
        sacc[i] = __builtin_amdgcn_mfma_f32_16x16x32_bf16(ak, bq_, sacc[i], 0, 0, 0);
      }
    }
    __builtin_amdgcn_s_setprio(0);
    // softmax (log2 domain), sacc scaled in place
#pragma unroll
    for (int i = 0; i < 4; ++i)
#pragma unroll
      for (int r = 0; r < 4; ++r) sacc[i][r] *= SCL;
    float mloc = sacc[0][0];
#pragma unroll
    for (int i = 0; i < 4; ++i)
#pragma unroll
      for (int r = 0; r < 4; ++r) mloc = fmaxf(mloc, sacc[i][r]);
    mloc = fmaxf(mloc, __shfl_xor(mloc, 16));
    mloc = fmaxf(mloc, __shfl_xor(mloc, 32));
    // T13 defer-max: keep old max unless growth > 10 (log2) anywhere in the wave.
    const bool resc = !__all(mloc <= m_prev + 10.f);
    float mnew = m_prev;
    if (resc) mnew = fmaxf(m_prev, mloc);
    float rsum = 0.f;
#pragma unroll
    for (int i = 0; i < 4; ++i) {
      float p0 = fexp2(sacc[i][0] - mnew);
      float p1 = fexp2(sacc[i][1] - mnew);
      float p2 = fexp2(sacc[i][2] - mnew);
      float p3 = fexp2(sacc[i][3] - mnew);
      rsum += (p0 + p1) + (p2 + p3);
      uintx2 pk = { cvtpk_bf16(p0, p1), cvtpk_bf16(p2, p3) };
      *(uintx2*)&Ps[(w*16 + l16)*PSTR + i*16 + quad*4] = pk;   // b64, bank-even
    }
    if (resc) {
      float alpha = fexp2(m_prev - mnew);
      m_prev = mnew;
      l_part *= alpha;
      float ab[4];
#pragma unroll
      for (int r = 0; r < 4; ++r) ab[r] = __shfl(alpha, quad*4 + r);
#pragma unroll
      for (int jd = 0; jd < 4; ++jd)
#pragma unroll
        for (int r = 0; r < 4; ++r) acc_o[jd][r] *= ab[r];
    }
    l_part += rsum;
    // O += P V : same-wave ds write->read is in-order
#pragma unroll
    for (int kk = 0; kk < 64; kk += 32) {
      bf16x8 ap = *(const bf16x8*)&Ps[(w*16 + l16)*PSTR + kk + quad*8];
      __builtin_amdgcn_s_setprio(1);
#pragma unroll
      for (int jd = 0; jd < 4; ++jd) {
        bf16x8 bv_ = *(const bf16x8*)&Vts[(jd*16 + l16)*PSTR + kk + quad*8];
        acc_o[jd] = __builtin_amdgcn_mfma_f32_16x16x32_bf16(ap, bv_, acc_o[jd], 0, 0, 0);
      }
      __builtin_amdgcn_s_setprio(0);
    }
  };

#pragma unroll
  for (int kt2 = 0; kt2 < 8; kt2 += 2) {
    STEP(ka, va, kb, vb, true);
    STEP(kb, vb, ka, va, kt2 + 1 < 7);
  }

  float l_tot = l_part;
  l_tot += __shfl_xor(l_tot, 16);
  l_tot += __shfl_xor(l_tot, 32);
  float lb[4];
#pragma unroll
  for (int r = 0; r < 4; ++r) lb[r] = 1.f / __shfl(l_tot, quad*4 + r);
#pragma unroll
  for (int jd = 0; jd < 4; ++jd) {
    const int d = jd*16 + l16;
#pragma unroll
    for (int r = 0; r < 4; ++r) {
      const int q = q0 + w*16 + quad*4 + r;
      ctx[(size_t)(b*S_ + q)*D_ + h*64 + d] = f2bf(acc_o[jd][r] * lb[r]);
    }
  }
}

// ---------------- residual + LayerNorm v2: wave-per-row, bf16 master chain ----------------
// 4 rows/block (one wave each), bf16x8 loads, shuffle-only reduction (no LDS/barrier).
// Lane covers cols lane*8..+7 (all lanes) and 512+lane*8..+7 (lanes<32).
// FIRST: residual read from fp32 hidden. LAST: write fp32 to d_out; else bf16 in-place xb.
template<bool FIRST, bool LAST>
__global__ __launch_bounds__(256) void ln_kernel(const float* __restrict__ residf,
                                                 __bf16* xb,           // resid in (l>0) + out (l<11); in-place
                                                 const __bf16* __restrict__ proj,
                                                 const float* __restrict__ gamma,
                                                 const float* __restrict__ beta,
                                                 float* __restrict__ xoutf) {
  const int tid = threadIdx.x;
  const int w = tid >> 6, lane = tid & 63;
  const int row = blockIdx.x*4 + w;
  const size_t base = (size_t)row * D_;
  const int c0 = lane*8;
  const bool has2 = lane < 32;
  const int c1 = 512 + lane*8;

  float v0[8], v1[8];
  {
    bf16x8 p0 = *(const bf16x8*)(proj + base + c0);
    if (FIRST) {
      float4 a = *(const float4*)(residf + base + c0);
      float4 bq4 = *(const float4*)(residf + base + c0 + 4);
      v0[0]=a.x+(float)p0[0]; v0[1]=a.y+(float)p0[1]; v0[2]=a.z+(float)p0[2]; v0[3]=a.w+(float)p0[3];
      v0[4]=bq4.x+(float)p0[4]; v0[5]=bq4.y+(float)p0[5]; v0[6]=bq4.z+(float)p0[6]; v0[7]=bq4.w+(float)p0[7];
    } else {
      bf16x8 r0 = *(const bf16x8*)(xb + base + c0);
#pragma unroll
      for (int j = 0; j < 8; ++j) v0[j] = (float)r0[j] + (float)p0[j];
    }
    if (has2) {
      bf16x8 p1 = *(const bf16x8*)(proj + base + c1);
      if (FIRST) {
        float4 a = *(const float4*)(residf + base + c1);
        float4 bq4 = *(const float4*)(residf + base + c1 + 4);
        v1[0]=a.x+(float)p1[0]; v1[1]=a.y+(float)p1[1]; v1[2]=a.z+(float)p1[2]; v1[3]=a.w+(float)p1[3];
        v1[4]=bq4.x+(float)p1[4]; v1[5]=bq4.y+(float)p1[5]; v1[6]=bq4.z+(float)p1[6]; v1[7]=bq4.w+(float)p1[7];
      } else {
        bf16x8 r1 = *(const bf16x8*)(xb + base + c1);
#pragma unroll
        for (int j = 0; j < 8; ++j) v1[j] = (float)r1[j] + (float)p1[j];
      }
    } else {
#pragma unroll
      for (int j = 0; j < 8; ++j) v1[j] = 0.f;
    }
  }
  float s = 0.f;
#pragma unroll
  for (int j = 0; j < 8; ++j) s += v0[j] + v1[j];
#pragma unroll
  for (int off = 32; off; off >>= 1) s += __shfl_xor(s, off);
  const float mu = s * (1.f/768.f);
  float q = 0.f;
#pragma unroll
  for (int j = 0; j < 8; ++j) { float d0 = v0[j]-mu; q += d0*d0; }
  if (has2) {
#pragma unroll
    for (int j = 0; j < 8; ++j) { float d1 = v1[j]-mu; q += d1*d1; }
  }
#pragma unroll
  for (int off = 32; off; off >>= 1) q += __shfl_xor(q, off);
  const float rs = rsqrtf(q * (1.f/768.f) + 1e-12f);

  {
    float4 g0 = *(const float4*)(gamma + c0);
    float4 g1 = *(const float4*)(gamma + c0 + 4);
    float4 b0 = *(const float4*)(beta + c0);
    float4 b1 = *(const float4*)(beta + c0 + 4);
    float o[8];
    o[0]=(v0[0]-mu)*rs*g0.x+b0.x; o[1]=(v0[1]-mu)*rs*g0.y+b0.y;
    o[2]=(v0[2]-mu)*rs*g0.z+b0.z; o[3]=(v0[3]-mu)*rs*g0.w+b0.w;
    o[4]=(v0[4]-mu)*rs*g1.x+b1.x; o[5]=(v0[5]-mu)*rs*g1.y+b1.y;
    o[6]=(v0[6]-mu)*rs*g1.z+b1.z; o[7]=(v0[7]-mu)*rs*g1.w+b1.w;
    if (LAST) {
      *(float4*)(xoutf + base + c0)     = {o[0],o[1],o[2],o[3]};
      *(float4*)(xoutf + base + c0 + 4) = {o[4],o[5],o[6],o[7]};
    } else {
      __bf16 ob[8];
#pragma unroll
      for (int j = 0; j < 8; ++j) ob[j] = f2bf(o[j]);
      *(bf16x8*)(xb + base + c0) = *(bf16x8*)ob;
    }
  }
  if (has2) {
    float4 g0 = *(const float4*)(gamma + c1);
    float4 g1 = *(const float4*)(gamma + c1 + 4);
    float4 b0 = *(const float4*)(beta + c1);
    float4 b1 = *(const float4*)(beta + c1 + 4);
    float o[8];
    o[0]=(v1[0]-mu)*rs*g0.x+b0.x; o[1]=(v1[1]-mu)*rs*g0.y+b0.y;
    o[2]=(v1[2]-mu)*rs*g0.z+b0.z; o[3]=(v1[3]-mu)*rs*g0.w+b0.w;
    o[4]=(v1[4]-mu)*rs*g1.x+b1.x; o[5]=(v1[5]-mu)*rs*g1.y+b1.y;
    o[6]=(v1[6]-mu)*rs*g1.z+b1.z; o[7]=(v1[7]-mu)*rs*g1.w+b1.w;
    if (LAST) {
      *(float4*)(xoutf + base + c1)     = {o[0],o[1],o[2],o[3]};
      *(float4*)(xoutf + base + c1 + 4) = {o[4],o[5],o[6],o[7]};
    } else {
      __bf16 ob[8];
#pragma unroll
      for (int j = 0; j < 8; ++j) ob[j] = f2bf(o[j]);
      *(bf16x8*)(xb + base + c1) = *(bf16x8*)ob;
    }
  }
}

extern "C" void kernel_launch(void* const* d_in, const int* in_sizes, int n_in,
                              void* d_out, int out_size, void* d_ws, size_t ws_size,
                              hipStream_t stream) {
  const float* hidden = (const float*)d_in[0];
  const float* router = (const float*)d_in[1];
  const float* qc[6]; const float* vc[6];
  for (int i = 0; i < 6; ++i) qc[i] = (const float*)d_in[2+i];
  for (int i = 0; i < 6; ++i) vc[i] = (const float*)d_in[8+i];
  const float* Wq = (const float*)d_in[14];
  const float* Wk = (const float*)d_in[15];
  const float* Wv = (const float*)d_in[16];
  const float* Wo = (const float*)d_in[17];
  const float* bq = (const float*)d_in[18];
  const float* bk = (const float*)d_in[19];
  const float* bv = (const float*)d_in[20];
  const float* bo = (const float*)d_in[21];
  const float* lns = (const float*)d_in[22];
  const float* lnb = (const float*)d_in[23];
  float* out = (float*)d_out;

  char* ws = (char*)d_ws;
  size_t off = 0;
  auto alloc = [&](size_t bytes) -> void* {
    off = (off + 255) & ~(size_t)255;
    void* p = ws + off; off += bytes; return p;
  };
  int*    e_idx = (int*)   alloc(4);
  float*  rpart = (float*) alloc((size_t)64*D_*4);
  __bf16* xbf   = (__bf16*)alloc((size_t)BS_*D_*2);
  __bf16* qkv   = (__bf16*)alloc((size_t)BS_*2304*2);
  __bf16* vt    = (__bf16*)alloc((size_t)B_*H_*64*S_*2);
  __bf16* ctx   = (__bf16*)alloc((size_t)BS_*D_*2);
  __bf16* projb = (__bf16*)alloc((size_t)BS_*D_*2);
  __bf16* wqkv  = (__bf16*)alloc((size_t)L_*2304*D_*2);
  __bf16* wobf  = (__bf16*)alloc((size_t)L_*D_*D_*2);
  (void)ws_size; (void)in_sizes; (void)n_in; (void)out_size;

  routing_pool_kernel<<<64, 256, 0, stream>>>(hidden, rpart);
  routing_finish_kernel<<<1, 256, 0, stream>>>(rpart, router, e_idx);
  convert_bf16_kernel<<<(BS_*D_)/2048, 256, 0, stream>>>(hidden, xbf);
  tt_prep_kernel<<<dim3(L_, 2, 16), 256, 0, stream>>>(qc[0],qc[1],qc[2],qc[3],qc[4],qc[5],
                                                      vc[0],vc[1],vc[2],vc[3],vc[4],vc[5],
                                                      Wq, Wv, e_idx, wqkv);
  convert_wk_kernel<<<(L_*D_*D_)/2048, 256, 0, stream>>>(Wk, wqkv);
  convert_bf16_kernel<<<(L_*D_*D_)/2048, 256, 0, stream>>>(Wo, wobf);

  for (int l = 0; l < L_; ++l) {
    gemm_bt<true><<<dim3(12,64), 512, 0, stream>>>(xbf, wqkv + (size_t)l*2304*D_,
        bq + l*D_, bk + l*D_, bv + l*D_, qkv, vt, 2304);
    flash_kernel<<<3072, 256, 0, stream>>>(qkv, vt, ctx);
    gemm_bt<false><<<dim3(4,64), 512, 0, stream>>>(ctx, wobf + (size_t)l*D_*D_,
        bo + l*D_, nullptr, nullptr, projb, nullptr, 768);
    if (l == 0)
      ln_kernel<true,false><<<BS_/4, 256, 0, stream>>>(hidden, xbf, projb,
          lns + l*D_, lnb + l*D_, nullptr);
    else if (l == L_-1)
      ln_kernel<false,true><<<BS_/4, 256, 0, stream>>>(nullptr, xbf, projb,
          lns + l*D_, lnb + l*D_, out);
    else
      ln_kernel<false,false><<<BS_/4, 256, 0, stream>>>(nullptr, xbf, projb,
          lns + l*D_, lnb + l*D_, nullptr);
  }
}

// Round 6
// 2251.668 us; speedup vs baseline: 1.1756x; 1.0010x over previous
//
#include <hip/hip_runtime.h>
#include <hip/hip_bf16.h>
#include <stdint.h>

#define E_ 8
#define L_ 12
#define D_ 768
#define H_ 12
#define S_ 512
#define B_ 32
#define BS_ (B_*S_)   // 16384

typedef __attribute__((ext_vector_type(4))) float floatx4;
typedef __attribute__((ext_vector_type(8))) __bf16 bf16x8;
typedef __attribute__((ext_vector_type(4))) __bf16 bf16x4;
typedef __attribute__((ext_vector_type(2))) unsigned uintx2;

__device__ __forceinline__ __bf16 f2bf(float f) {
  unsigned u = __builtin_bit_cast(unsigned, f);
  u += 0x7fffu + ((u >> 16) & 1u);           // RNE
  unsigned short h = (unsigned short)(u >> 16);
  return __builtin_bit_cast(__bf16, h);
}

// HW packed f32x2 -> bf16x2 (RNE). Strict win over 2x manual f2bf (4 VALU each).
__device__ __forceinline__ unsigned cvtpk_bf16(float lo, float hi) {
  unsigned r;
  asm("v_cvt_pk_bf16_f32 %0, %1, %2" : "=v"(r) : "v"(lo), "v"(hi));
  return r;
}

__device__ __forceinline__ float fexp2(float x) {
#if __has_builtin(__builtin_amdgcn_exp2f)
  return __builtin_amdgcn_exp2f(x);
#else
  return exp2f(x);
#endif
}

__device__ __forceinline__ void async16(const void* g, void* l) {
  __builtin_amdgcn_global_load_lds((__attribute__((address_space(1))) void*)g,
                                   (__attribute__((address_space(3))) void*)l,
                                   16, 0, 0);
}

// ---------------- routing stage 1: 64 blocks x 8 rows, coalesced partial sums ----------------
__global__ void routing_pool_kernel(const float* __restrict__ hidden,
                                    float* __restrict__ partial) {
  const int blk = blockIdx.x;    // 0..63
  const int tid = threadIdx.x;
  const float* base = hidden + (size_t)(B_-1)*S_*D_ + (size_t)blk*8*D_;
  float acc[3] = {0.f, 0.f, 0.f};
  for (int s = 0; s < 8; ++s) {
#pragma unroll
    for (int i = 0; i < 3; ++i)
      acc[i] += base[(size_t)s*D_ + tid + i*256];
  }
#pragma unroll
  for (int i = 0; i < 3; ++i) partial[(size_t)blk*D_ + tid + i*256] = acc[i];
}

// ---------------- routing stage 2: reduce partials, logits, argmax ----------------
__global__ void routing_finish_kernel(const float* __restrict__ partial,
                                      const float* __restrict__ rw,
                                      int* __restrict__ e_out) {
  __shared__ float pooled[D_];
  __shared__ float logits[E_];
  int tid = threadIdx.x;
#pragma unroll
  for (int i = 0; i < 3; ++i) {
    int d = tid + i*256;
    float s = 0.f;
    for (int blk = 0; blk < 64; ++blk) s += partial[(size_t)blk*D_ + d];
    pooled[d] = s;  // positive scale factor irrelevant for argmax
  }
  __syncthreads();
  if (tid < E_) {
    float s = 0.f;
    for (int d = 0; d < D_; ++d) s += pooled[d] * rw[d*E_ + tid];
    logits[tid] = s;
  }
  __syncthreads();
  if (tid == 0) {
    int best = 0; float bvv = logits[0];
    for (int e = 1; e < E_; ++e) if (logits[e] > bvv) { bvv = logits[e]; best = e; }
    e_out[0] = best;
  }
}

// ---------------- fp32 -> bf16 convert (n multiple of 2048) ----------------
__global__ void convert_bf16_kernel(const float* __restrict__ src, __bf16* __restrict__ dst) {
  size_t i = ((size_t)blockIdx.x*256 + threadIdx.x)*8;
  __bf16 r[8];
#pragma unroll
  for (int j = 0; j < 8; ++j) r[j] = f2bf(src[i+j]);
  *(bf16x8*)(dst + i) = *(bf16x8*)r;
}

// Wk [L][768][768] fp32 -> rows 768..1535 of wqkv [L][2304][768] bf16
__global__ void convert_wk_kernel(const float* __restrict__ wk, __bf16* __restrict__ wqkv) {
  size_t i = ((size_t)blockIdx.x*256 + threadIdx.x)*8;
  int l = (int)(i / (D_*D_));
  int rem = (int)(i % (D_*D_));
  int n = rem / D_, k = rem % D_;
  __bf16 r[8];
#pragma unroll
  for (int j = 0; j < 8; ++j) r[j] = f2bf(wk[i+j]);
  *(bf16x8*)(wqkv + (size_t)l*2304*D_ + (size_t)(768+n)*D_ + k) = *(bf16x8*)r;
}

// ---------------- TT adapter build: Wq_a / Wv_a -> wqkv bf16 ----------------
__global__ void tt_prep_kernel(
    const float* __restrict__ qc0, const float* __restrict__ qc1, const float* __restrict__ qc2,
    const float* __restrict__ qc3, const float* __restrict__ qc4, const float* __restrict__ qc5,
    const float* __restrict__ vc0, const float* __restrict__ vc1, const float* __restrict__ vc2,
    const float* __restrict__ vc3, const float* __restrict__ vc4, const float* __restrict__ vc5,
    const float* __restrict__ Wq, const float* __restrict__ Wv,
    const int* __restrict__ e_idx, __bf16* __restrict__ wqkv) {
  const int l = blockIdx.x;
  const int pre = blockIdx.y;         // 0 = q, 1 = v
  const int z = blockIdx.z;           // 0..15 -> rows 48z..48z+47
  const int tid = threadIdx.x;
  const int e = e_idx[0];
  const float* c0 = (pre ? vc0 : qc0) + (size_t)(e*L_ + l)*96;   // [12][8]
  const float* c1 = (pre ? vc1 : qc1) + (size_t)(e*L_ + l)*512;  // [8][8][8]
  const float* c2 = (pre ? vc2 : qc2) + (size_t)(e*L_ + l)*512;
  const float* c3 = (pre ? vc3 : qc3) + (size_t)(e*L_ + l)*512;
  const float* c4 = (pre ? vc4 : qc4) + (size_t)(e*L_ + l)*512;
  const float* c5 = (pre ? vc5 : qc5) + (size_t)(e*L_ + l)*96;   // [8][12]
  __shared__ float M1[768];   // [j][l2][m]
  __shared__ float R2[768];   // [q][r][t]
  __shared__ float M2[6144];  // [out][o]
  __shared__ float Rm[6144];  // [o][in]
  for (int idx = tid; idx < 768; idx += 256) {
    int j = idx >> 6, rem = idx & 63, l2 = rem >> 3, m = rem & 7;
    float s = 0.f;
    for (int k = 0; k < 8; ++k) s += c0[j*8 + k] * c1[k*64 + l2*8 + m];
    M1[idx] = s;
    int qq = idx / 96, rem2 = idx % 96, rr = rem2 / 12, t = rem2 % 12;
    float s2 = 0.f;
    for (int si = 0; si < 8; ++si) s2 += c4[qq*64 + rr*8 + si] * c5[si*12 + t];
    R2[idx] = s2;
  }
  __syncthreads();
  for (int idx = tid; idx < 6144; idx += 256) {
    int o = idx & 7, n = (idx >> 3) & 7, jl = idx >> 6;
    float s = 0.f;
    for (int m = 0; m < 8; ++m) s += M1[jl*8 + m] * c2[m*64 + n*8 + o];
    M2[idx] = s;
    int o2 = idx / 768, inp = idx % 768, p = inp / 96, rt = inp % 96;
    float s2 = 0.f;
    for (int qq = 0; qq < 8; ++qq) s2 += c3[o2*64 + p*8 + qq] * R2[qq*96 + rt];
    Rm[idx] = s2;
  }
  __syncthreads();
  const float* Wbase = (pre ? Wv : Wq) + (size_t)l*D_*D_;
  __bf16* dst = wqkv + (size_t)l*2304*D_ + (pre ? (size_t)1536*D_ : 0);
  for (int g = tid; g < 48*96; g += 256) {
    const int outr = z*48 + (g / 96);
    const int inp0 = (g % 96) * 8;
    float m2r[8];
#pragma unroll
    for (int o = 0; o < 8; ++o) m2r[o] = M2[outr*8 + o];
    float acc[8];
#pragma unroll
    for (int u = 0; u < 8; ++u) acc[u] = 0.f;
#pragma unroll
    for (int o = 0; o < 8; ++o) {
      float4 r0 = *(const float4*)&Rm[o*768 + inp0];
      float4 r1 = *(const float4*)&Rm[o*768 + inp0 + 4];
      acc[0] += m2r[o]*r0.x; acc[1] += m2r[o]*r0.y;
      acc[2] += m2r[o]*r0.z; acc[3] += m2r[o]*r0.w;
      acc[4] += m2r[o]*r1.x; acc[5] += m2r[o]*r1.y;
      acc[6] += m2r[o]*r1.z; acc[7] += m2r[o]*r1.w;
    }
    const float* wb = Wbase + (size_t)outr*768 + inp0;
    float4 w0 = *(const float4*)wb;
    float4 w1 = *(const float4*)(wb + 4);
    __bf16 r[8];
    r[0] = f2bf(w0.x + 8.f*acc[0]); r[1] = f2bf(w0.y + 8.f*acc[1]);
    r[2] = f2bf(w0.z + 8.f*acc[2]); r[3] = f2bf(w0.w + 8.f*acc[3]);
    r[4] = f2bf(w1.x + 8.f*acc[4]); r[5] = f2bf(w1.y + 8.f*acc[5]);
    r[6] = f2bf(w1.z + 8.f*acc[6]); r[7] = f2bf(w1.w + 8.f*acc[7]);
    *(bf16x8*)(dst + (size_t)outr*768 + inp0) = *(bf16x8*)r;
  }
}

// ---------------- bf16 MFMA GEMM v5: 128x192 tile, 4 waves, ring-4, 2 blocks/CU ----------------
// R11: R7's schedule VERBATIM (ring-4, prefetch distance 3, counted vmcnt never 0,
// split 12-MFMA clusters, T2 line-XOR swizzle, T5 setprio), re-parameterized so TWO
// independent blocks co-reside per CU (R8's failure causes removed):
//  - 4 waves (256 thr), wave-tile 128x48 (wn=w, wm=0) -- same 11-read/24-MFMA reuse.
//  - Slot 20 KiB, ring-4 = 80 KiB -> exactly 2 blocks/CU (160 KiB LDS). The other
//    block's waves cover barrier/vmcnt stalls (m114 TLP mechanism).
//  - Grid: QKV (12,128) = 1536 = exactly 3 co-resident rounds of 512; proj (4,128)
//    = 512 = exactly 1 round. No quantization tax (R8's 1.125-round mistake).
//  - Uniform staging: 20 x 1 KiB calls/step, wave w takes calls w*5..w*5+4 (c<8 = A
//    lines, else B lines) -> single steady vmcnt(10) (2 tiles x 5 calls in flight).
#define SLOT_BYTES 20480
template<bool SPLITV>
__global__ __launch_bounds__(256, 2) void gemm_bt(
    const __bf16* __restrict__ A, const __bf16* __restrict__ Bw,
    const float* __restrict__ bq, const float* __restrict__ bk, const float* __restrict__ bvp,
    __bf16* __restrict__ outb, __bf16* __restrict__ vtout, int Nw) {
  __shared__ __align__(16) char lds[4*SLOT_BYTES];   // 80 KiB -> 2 blocks/CU
  const int tid = threadIdx.x;
  const int w = tid >> 6, lane = tid & 63;
  const int quad = lane >> 4, l16 = lane & 15;
  const size_t mblk = (size_t)blockIdx.y * 128;
  const size_t nblk = (size_t)blockIdx.x * 192;
  const __bf16* Ag = A + mblk * 768;
  const __bf16* Bg = Bw + nblk * 768;

  // ---- staging: 20 calls of 1 KiB (8 x 128-B lines each). Call c = w*5+i.
  // c<8: A region (lines 0..63, rows 0..127); c>=8: B region (lines 0..95, rows 0..191).
  // Row pairs packed in 128-B lines; s8 = (row&1)*4+kseg, phys = s8 ^ (line&7); swizzle
  // folded into the per-lane GLOBAL source, LDS dest linear (rule #21).
  const __bf16* gbase[5];
  int loff[5];
#pragma unroll
  for (int i = 0; i < 5; ++i) {
    int c = w*5 + i;
    bool isA = c < 8;
    int lb = isA ? c*8 : (c-8)*8;                 // line base within region
    int line = lb + (lane >> 3);
    int s8 = (lane & 7) ^ (line & 7);
    int row = 2*line + (s8 >> 2);
    gbase[i] = (isA ? Ag : Bg) + row*768 + (s8 & 3)*8;
    loff[i] = (isA ? 0 : 8192) + lb*128;          // bytes; HW appends lane*16
  }

  // ---- fragment ds_read byte offsets (swizzled; max 2-way bank aliasing = free)
  int a_foff[8], b_foff[3];
#pragma unroll
  for (int mf = 0; mf < 8; ++mf) {
    int r = mf*16 + l16;                          // 0..127
    int line = r >> 1, s8 = (r & 1)*4 + quad, ph = s8 ^ (line & 7);
    a_foff[mf] = line*128 + ph*16;
  }
#pragma unroll
  for (int nf = 0; nf < 3; ++nf) {
    int r = w*48 + nf*16 + l16;                   // 0..191
    int line = r >> 1, s8 = (r & 1)*4 + quad, ph = s8 ^ (line & 7);
    b_foff[nf] = 8192 + line*128 + ph*16;
  }

  floatx4 acc[8][3];
#pragma unroll
  for (int mf = 0; mf < 8; ++mf)
#pragma unroll
    for (int nf = 0; nf < 3; ++nf) acc[mf][nf] = {0.f,0.f,0.f,0.f};

  auto STAGE = [&](int t) {
    char* ls = lds + (t & 3)*SLOT_BYTES;
#pragma unroll
    for (int i = 0; i < 5; ++i) async16(gbase[i] + t*32, ls + loff[i]);
  };

  bf16x8 af[8], bfr[3];
  auto LOAD1 = [&](int u) {
    const char* ls = lds + (u & 3)*SLOT_BYTES;
#pragma unroll
    for (int nf = 0; nf < 3; ++nf) bfr[nf] = *(const bf16x8*)(ls + b_foff[nf]);
#pragma unroll
    for (int mf = 0; mf < 4; ++mf) af[mf] = *(const bf16x8*)(ls + a_foff[mf]);
  };
  auto LOAD2 = [&](int u) {
    const char* ls = lds + (u & 3)*SLOT_BYTES;
#pragma unroll
    for (int mf = 4; mf < 8; ++mf) af[mf] = *(const bf16x8*)(ls + a_foff[mf]);
  };
  auto MM = [&](int mf0) {
    __builtin_amdgcn_s_setprio(1);
#pragma unroll
    for (int mf = mf0; mf < mf0 + 4; ++mf)
#pragma unroll
      for (int nf = 0; nf < 3; ++nf)
        acc[mf][nf] = __builtin_amdgcn_mfma_f32_16x16x32_bf16(af[mf], bfr[nf], acc[mf][nf], 0, 0, 0);
    __builtin_amdgcn_s_setprio(0);
  };
  auto BAR = [&]() {
    __builtin_amdgcn_s_barrier();
    __builtin_amdgcn_sched_barrier(0);
  };

  // ---- prologue: 3 subtiles in flight; validate subtile 0
  STAGE(0); STAGE(1); STAGE(2);
  asm volatile("s_waitcnt vmcnt(10)" ::: "memory");
  BAR();

  // ---- main loop: u = 0..20 (STAGE(u+3) valid, steady vmcnt(10))
  for (int u = 0; u < 21; ++u) {
    LOAD1(u);
    BAR();
    MM(0);
    LOAD2(u);
    STAGE(u + 3);
    asm volatile("s_waitcnt vmcnt(10)" ::: "memory");
    BAR();
    MM(4);
  }
  // ---- u = 21: no stage; validate 22
  LOAD1(21);
  BAR();
  MM(0);
  LOAD2(21);
  asm volatile("s_waitcnt vmcnt(5)" ::: "memory");
  BAR();
  MM(4);
  // ---- u = 22: validate 23
  LOAD1(22);
  BAR();
  MM(0);
  LOAD2(22);
  asm volatile("s_waitcnt vmcnt(0)" ::: "memory");
  BAR();
  MM(4);
  // ---- u = 23: final
  LOAD1(23);
  BAR();
  MM(0);
  LOAD2(23);
  BAR();
  MM(4);

  // ---- epilogue
  if (SPLITV && blockIdx.x >= 8) {
    // V region (cols 1536..2303): bias + transpose-write into vt[bh][64][512]
#pragma unroll
    for (int nf = 0; nf < 3; ++nf) {
      const int vcol = (int)nblk - 1536 + w*48 + nf*16 + l16;   // 0..767
      const int h = vcol >> 6, d = vcol & 63;
      const float bval = bvp[vcol];
#pragma unroll
      for (int mf = 0; mf < 8; ++mf) {
        const int mrow = (int)mblk + mf*16 + quad*4;            // r=0 base
        const int b = mrow >> 9, s = mrow & 511;
        __bf16 pr[4];
#pragma unroll
        for (int r = 0; r < 4; ++r) pr[r] = f2bf(acc[mf][nf][r] + bval);
        *(bf16x4*)(vtout + (size_t)((b*H_ + h)*64 + d)*S_ + s) = *(bf16x4*)pr;
      }
    }
    return;
  }
  const float* bias = bq;
  if (SPLITV) bias = (blockIdx.x < 4) ? bq : bk;
  float bval[3]; int ncol[3];
#pragma unroll
  for (int nf = 0; nf < 3; ++nf) {
    ncol[nf] = (int)nblk + w*48 + nf*16 + l16;
    int bc = ncol[nf]; if (bc >= 768) bc -= 768;
    bval[nf] = bias[bc];
  }
#pragma unroll
  for (int mf = 0; mf < 8; ++mf) {
#pragma unroll
    for (int nf = 0; nf < 3; ++nf) {
#pragma unroll
      for (int r = 0; r < 4; ++r) {
        const int mrow = (int)mblk + mf*16 + quad*4 + r;
        outb[(size_t)mrow*Nw + ncol[nf]] = f2bf(acc[mf][nf][r] + bval[nf]);
      }
    }
  }
}

// ---------------- flash attention v4: VALU-diet (R10-proven: 85 -> <79 us) ----------------
//  - Q fragments in registers (loop-invariant); Qs LDS deleted.
//  - P pack via v_cvt_pk_bf16_f32; T13 defer-max (THR=10 log2); pointer-bump prefetch;
//    reciprocal epilogue. T14 pipeline: K/V kt+1 -> regs during kt compute; raw
//    s_barrier + lgkmcnt(0)-only; sched_barrier(0) after each barrier (rule #18).
#define PSTR 72   // padded LDS row stride (bf16): 144 B
__global__ __launch_bounds__(256, 4) void flash_kernel(const __bf16* __restrict__ qkv,
                                                       const __bf16* __restrict__ vt,
                                                       __bf16* __restrict__ ctx) {
  __shared__ __align__(16) __bf16 Ks[64*PSTR];    // [kv][d]
  __shared__ __align__(16) __bf16 Vts[64*PSTR];   // [d][kv]
  __shared__ __align__(16) __bf16 Ps[64*PSTR];    // [q][kv], wave w owns rows w*16..+15
  const int tid = threadIdx.x;
  const int w = tid >> 6, lane = tid & 63;
  const int quad = lane >> 4, l16 = lane & 15;
  const int n = blockIdx.x;
  const int bh = (n >> 6)*8 + (n & 7);
  const int q0 = ((n >> 3) & 7) * 64;
  const int b = bh / H_, h = bh % H_;
  const float SCL = 0.125f * 1.44269504f;  // 1/sqrt(64) * log2(e)

  // per-thread staging slot (row, seg) for K/V tiles: 2 slots x 16 B
  const int row0 = tid >> 3,         seg0 = tid & 7;        // rows 0..31
  const int row1 = (256 + tid) >> 3, seg1 = tid & 7;        // rows 32..63

  // ---- prologue: issue K/V loads for kt=0
  bf16x8 ka[2], va[2], kb[2], vb[2];
  ka[0] = *(const bf16x8*)(qkv + (size_t)(b*S_ + row0)*2304 + 768 + h*64 + seg0*8);
  va[0] = *(const bf16x8*)(vt  + (size_t)(bh*64 + row0)*S_ + seg0*8);
  ka[1] = *(const bf16x8*)(qkv + (size_t)(b*S_ + row1)*2304 + 768 + h*64 + seg1*8);
  va[1] = *(const bf16x8*)(vt  + (size_t)(bh*64 + row1)*S_ + seg1*8);

  // ---- Q fragments straight to registers (loop-invariant): row q0+w*16+l16,
  // d = kk + quad*8 .. +7 for kk = 0, 32 -- exactly the B-operand fragment layout.
  bf16x8 qf0, qf1;
  {
    const __bf16* qrow = qkv + (size_t)(b*S_ + q0 + w*16 + l16)*2304 + h*64 + quad*8;
    qf0 = *(const bf16x8*)qrow;
    qf1 = *(const bf16x8*)(qrow + 32);
  }

  // prefetch pointers (kt=1 bases), bumped by constant strides
  const __bf16* kp0 = qkv + (size_t)(b*S_ + 64 + row0)*2304 + 768 + h*64 + seg0*8;
  const __bf16* kp1 = qkv + (size_t)(b*S_ + 64 + row1)*2304 + 768 + h*64 + seg1*8;
  const __bf16* vp0 = vt  + (size_t)(bh*64 + row0)*S_ + 64 + seg0*8;
  const __bf16* vp1 = vt  + (size_t)(bh*64 + row1)*S_ + 64 + seg1*8;

  floatx4 acc_o[4];   // C[m=q_local=quad*4+r][n=d=jd*16+l16]
#pragma unroll
  for (int jd = 0; jd < 4; ++jd) acc_o[jd] = {0.f,0.f,0.f,0.f};
  float m_prev = -__builtin_inff();   // per-lane q = w*16 + l16 (log2 domain)
  float l_part = 0.f;                 // per-quad partial of the softmax denom

  auto STEP = [&](bf16x8* ck, bf16x8* cv, bf16x8* nk, bf16x8* nv, bool pf) {
    // barrier #1: previous tile's Ks/Vts reads are consumed (lgkm drained per-wave)
    asm volatile("s_waitcnt lgkmcnt(0)" ::: "memory");
    __builtin_amdgcn_s_barrier();
    __builtin_amdgcn_sched_barrier(0);
    // write current K/V regs -> LDS (compiler inserts the vmcnt wait on their loads,
    // issued one full compute phase ago)
    *(bf16x8*)&Ks[row0*PSTR + seg0*8]  = ck[0];
    *(bf16x8*)&Vts[row0*PSTR + seg0*8] = cv[0];
    *(bf16x8*)&Ks[row1*PSTR + seg1*8]  = ck[1];
    *(bf16x8*)&Vts[row1*PSTR + seg1*8] = cv[1];
    // prefetch next tile into regs (issue only; consumed next STEP)
    if (pf) {
      nk[0] = *(const bf16x8*)kp0; kp0 += 64*2304;
      nv[0] = *(const bf16x8*)vp0; vp0 += 64;
      nk[1] = *(const bf16x8*)kp1; kp1 += 64*2304;
      nv[1] = *(const bf16x8*)vp1; vp1 += 64;
    }
    // barrier #2: ds_writes visible; prefetch loads REMAIN in flight
    asm volatile("s_waitcnt lgkmcnt(0)" ::: "memory");
    __builtin_amdgcn_s_barrier();
    __builtin_amdgcn_sched_barrier(0);

    // S^T tile: mfma(A=K, B=Q) -> C[m=kv=i*16+quad*4+r][n=q=w*16+l16]
    floatx4 sacc[4];
#pragma unroll
    for (int i = 0; i < 4; ++i) sacc[i] = {0.f,0.f,0.f,0.f};
    __builtin_amdgcn_s_setprio(1);
#pragma unroll
    for (int kk = 0; kk < 64; kk += 32) {
      bf16x8 bq_ = kk ? qf1 : qf0;
#pragma unroll
      for (int i = 0; i < 4; ++i) {
        bf16x8 ak = *(const bf16x8*)&Ks[(i*16 + l16)*PSTR + kk + quad*8];
        sacc[i] = __builtin_amdgcn_mfma_f32_16x16x32_bf16(ak, bq_, sacc[i], 0, 0, 0);
      }
    }
    __builtin_amdgcn_s_setprio(0);
    // softmax (log2 domain), sacc scaled in place
#pragma unroll
    for (int i = 0; i < 4; ++i)
#pragma unroll
      for (int r = 0; r < 4; ++r) sacc[i][r] *= SCL;
    float mloc = sacc[0][0];
#pragma unroll
    for (int i = 0; i < 4; ++i)
#pragma unroll
      for (int r = 0; r < 4; ++r) mloc = fmaxf(mloc, sacc[i][r]);
    mloc = fmaxf(mloc, __shfl_xor(mloc, 16));
    mloc = fmaxf(mloc, __shfl_xor(mloc, 32));
    // T13 defer-max: keep old max unless growth > 10 (log2) anywhere in the wave.
    const bool resc = !__all(mloc <= m_prev + 10.f);
    float mnew = m_prev;
    if (resc) mnew = fmaxf(m_prev, mloc);
    float rsum = 0.f;
#pragma unroll
    for (int i = 0; i < 4; ++i) {
      float p0 = fexp2(sacc[i][0] - mnew);
      float p1 = fexp2(sacc[i][1] - mnew);
      float p2 = fexp2(sacc[i][2] - mnew);
      float p3 = fexp2(sacc[i][3] - mnew);
      rsum += (p0 + p1) + (p2 + p3);
      uintx2 pk = { cvtpk_bf16(p0, p1), cvtpk_bf16(p2, p3) };
      *(uintx2*)&Ps[(w*16 + l16)*PSTR + i*16 + quad*4] = pk;   // b64, bank-even
    }
    if (resc) {
      float alpha = fexp2(m_prev - mnew);
      m_prev = mnew;
      l_part *= alpha;
      float ab[4];
#pragma unroll
      for (int r = 0; r < 4; ++r) ab[r] = __shfl(alpha, quad*4 + r);
#pragma unroll
      for (int jd = 0; jd < 4; ++jd)
#pragma unroll
        for (int r = 0; r < 4; ++r) acc_o[jd][r] *= ab[r];
    }
    l_part += rsum;
    // O += P V : same-wave ds write->read is in-order
#pragma unroll
    for (int kk = 0; kk < 64; kk += 32) {
      bf16x8 ap = *(const bf16x8*)&Ps[(w*16 + l16)*PSTR + kk + quad*8];
      __builtin_amdgcn_s_setprio(1);
#pragma unroll
      for (int jd = 0; jd < 4; ++jd) {
        bf16x8 bv_ = *(const bf16x8*)&Vts[(jd*16 + l16)*PSTR + kk + quad*8];
        acc_o[jd] = __builtin_amdgcn_mfma_f32_16x16x32_bf16(ap, bv_, acc_o[jd], 0, 0, 0);
      }
      __builtin_amdgcn_s_setprio(0);
    }
  };

#pragma unroll
  for (int kt2 = 0; kt2 < 8; kt2 += 2) {
    STEP(ka, va, kb, vb, true);
    STEP(kb, vb, ka, va, kt2 + 1 < 7);
  }

  float l_tot = l_part;
  l_tot += __shfl_xor(l_tot, 16);
  l_tot += __shfl_xor(l_tot, 32);
  float lb[4];
#pragma unroll
  for (int r = 0; r < 4; ++r) lb[r] = 1.f / __shfl(l_tot, quad*4 + r);
#pragma unroll
  for (int jd = 0; jd < 4; ++jd) {
    const int d = jd*16 + l16;
#pragma unroll
    for (int r = 0; r < 4; ++r) {
      const int q = q0 + w*16 + quad*4 + r;
      ctx[(size_t)(b*S_ + q)*D_ + h*64 + d] = f2bf(acc_o[jd][r] * lb[r]);
    }
  }
}

// ---------------- residual + LayerNorm v2: wave-per-row, bf16 master chain ----------------
// 4 rows/block (one wave each), bf16x8 loads, shuffle-only reduction (no LDS/barrier).
// Lane covers cols lane*8..+7 (all lanes) and 512+lane*8..+7 (lanes<32).
// FIRST: residual read from fp32 hidden. LAST: write fp32 to d_out; else bf16 in-place xb.
template<bool FIRST, bool LAST>
__global__ __launch_bounds__(256) void ln_kernel(const float* __restrict__ residf,
                                                 __bf16* xb,           // resid in (l>0) + out (l<11); in-place
                                                 const __bf16* __restrict__ proj,
                                                 const float* __restrict__ gamma,
                                                 const float* __restrict__ beta,
                                                 float* __restrict__ xoutf) {
  const int tid = threadIdx.x;
  const int w = tid >> 6, lane = tid & 63;
  const int row = blockIdx.x*4 + w;
  const size_t base = (size_t)row * D_;
  const int c0 = lane*8;
  const bool has2 = lane < 32;
  const int c1 = 512 + lane*8;

  float v0[8], v1[8];
  {
    bf16x8 p0 = *(const bf16x8*)(proj + base + c0);
    if (FIRST) {
      float4 a = *(const float4*)(residf + base + c0);
      float4 bq4 = *(const float4*)(residf + base + c0 + 4);
      v0[0]=a.x+(float)p0[0]; v0[1]=a.y+(float)p0[1]; v0[2]=a.z+(float)p0[2]; v0[3]=a.w+(float)p0[3];
      v0[4]=bq4.x+(float)p0[4]; v0[5]=bq4.y+(float)p0[5]; v0[6]=bq4.z+(float)p0[6]; v0[7]=bq4.w+(float)p0[7];
    } else {
      bf16x8 r0 = *(const bf16x8*)(xb + base + c0);
#pragma unroll
      for (int j = 0; j < 8; ++j) v0[j] = (float)r0[j] + (float)p0[j];
    }
    if (has2) {
      bf16x8 p1 = *(const bf16x8*)(proj + base + c1);
      if (FIRST) {
        float4 a = *(const float4*)(residf + base + c1);
        float4 bq4 = *(const float4*)(residf + base + c1 + 4);
        v1[0]=a.x+(float)p1[0]; v1[1]=a.y+(float)p1[1]; v1[2]=a.z+(float)p1[2]; v1[3]=a.w+(float)p1[3];
        v1[4]=bq4.x+(float)p1[4]; v1[5]=bq4.y+(float)p1[5]; v1[6]=bq4.z+(float)p1[6]; v1[7]=bq4.w+(float)p1[7];
      } else {
        bf16x8 r1 = *(const bf16x8*)(xb + base + c1);
#pragma unroll
        for (int j = 0; j < 8; ++j) v1[j] = (float)r1[j] + (float)p1[j];
      }
    } else {
#pragma unroll
      for (int j = 0; j < 8; ++j) v1[j] = 0.f;
    }
  }
  float s = 0.f;
#pragma unroll
  for (int j = 0; j < 8; ++j) s += v0[j] + v1[j];
#pragma unroll
  for (int off = 32; off; off >>= 1) s += __shfl_xor(s, off);
  const float mu = s * (1.f/768.f);
  float q = 0.f;
#pragma unroll
  for (int j = 0; j < 8; ++j) { float d0 = v0[j]-mu; q += d0*d0; }
  if (has2) {
#pragma unroll
    for (int j = 0; j < 8; ++j) { float d1 = v1[j]-mu; q += d1*d1; }
  }
#pragma unroll
  for (int off = 32; off; off >>= 1) q += __shfl_xor(q, off);
  const float rs = rsqrtf(q * (1.f/768.f) + 1e-12f);

  {
    float4 g0 = *(const float4*)(gamma + c0);
    float4 g1 = *(const float4*)(gamma + c0 + 4);
    float4 b0 = *(const float4*)(beta + c0);
    float4 b1 = *(const float4*)(beta + c0 + 4);
    float o[8];
    o[0]=(v0[0]-mu)*rs*g0.x+b0.x; o[1]=(v0[1]-mu)*rs*g0.y+b0.y;
    o[2]=(v0[2]-mu)*rs*g0.z+b0.z; o[3]=(v0[3]-mu)*rs*g0.w+b0.w;
    o[4]=(v0[4]-mu)*rs*g1.x+b1.x; o[5]=(v0[5]-mu)*rs*g1.y+b1.y;
    o[6]=(v0[6]-mu)*rs*g1.z+b1.z; o[7]=(v0[7]-mu)*rs*g1.w+b1.w;
    if (LAST) {
      *(float4*)(xoutf + base + c0)     = {o[0],o[1],o[2],o[3]};
      *(float4*)(xoutf + base + c0 + 4) = {o[4],o[5],o[6],o[7]};
    } else {
      __bf16 ob[8];
#pragma unroll
      for (int j = 0; j < 8; ++j) ob[j] = f2bf(o[j]);
      *(bf16x8*)(xb + base + c0) = *(bf16x8*)ob;
    }
  }
  if (has2) {
    float4 g0 = *(const float4*)(gamma + c1);
    float4 g1 = *(const float4*)(gamma + c1 + 4);
    float4 b0 = *(const float4*)(beta + c1);
    float4 b1 = *(const float4*)(beta + c1 + 4);
    float o[8];
    o[0]=(v1[0]-mu)*rs*g0.x+b0.x; o[1]=(v1[1]-mu)*rs*g0.y+b0.y;
    o[2]=(v1[2]-mu)*rs*g0.z+b0.z; o[3]=(v1[3]-mu)*rs*g0.w+b0.w;
    o[4]=(v1[4]-mu)*rs*g1.x+b1.x; o[5]=(v1[5]-mu)*rs*g1.y+b1.y;
    o[6]=(v1[6]-mu)*rs*g1.z+b1.z; o[7]=(v1[7]-mu)*rs*g1.w+b1.w;
    if (LAST) {
      *(float4*)(xoutf + base + c1)     = {o[0],o[1],o[2],o[3]};
      *(float4*)(xoutf + base + c1 + 4) = {o[4],o[5],o[6],o[7]};
    } else {
      __bf16 ob[8];
#pragma unroll
      for (int j = 0; j < 8; ++j) ob[j] = f2bf(o[j]);
      *(bf16x8*)(xb + base + c1) = *(bf16x8*)ob;
    }
  }
}

extern "C" void kernel_launch(void* const* d_in, const int* in_sizes, int n_in,
                              void* d_out, int out_size, void* d_ws, size_t ws_size,
                              hipStream_t stream) {
  const float* hidden = (const float*)d_in[0];
  const float* router = (const float*)d_in[1];
  const float* qc[6]; const float* vc[6];
  for (int i = 0; i < 6; ++i) qc[i] = (const float*)d_in[2+i];
  for (int i = 0; i < 6; ++i) vc[i] = (const float*)d_in[8+i];
  const float* Wq = (const float*)d_in[14];
  const float* Wk = (const float*)d_in[15];
  const float* Wv = (const float*)d_in[16];
  const float* Wo = (const float*)d_in[17];
  const float* bq = (const float*)d_in[18];
  const float* bk = (const float*)d_in[19];
  const float* bv = (const float*)d_in[20];
  const float* bo = (const float*)d_in[21];
  const float* lns = (const float*)d_in[22];
  const float* lnb = (const float*)d_in[23];
  float* out = (float*)d_out;

  char* ws = (char*)d_ws;
  size_t off = 0;
  auto alloc = [&](size_t bytes) -> void* {
    off = (off + 255) & ~(size_t)255;
    void* p = ws + off; off += bytes; return p;
  };
  int*    e_idx = (int*)   alloc(4);
  float*  rpart = (float*) alloc((size_t)64*D_*4);
  __bf16* xbf   = (__bf16*)alloc((size_t)BS_*D_*2);
  __bf16* qkv   = (__bf16*)alloc((size_t)BS_*2304*2);
  __bf16* vt    = (__bf16*)alloc((size_t)B_*H_*64*S_*2);
  __bf16* ctx   = (__bf16*)alloc((size_t)BS_*D_*2);
  __bf16* projb = (__bf16*)alloc((size_t)BS_*D_*2);
  __bf16* wqkv  = (__bf16*)alloc((size_t)L_*2304*D_*2);
  __bf16* wobf  = (__bf16*)alloc((size_t)L_*D_*D_*2);
  (void)ws_size; (void)in_sizes; (void)n_in; (void)out_size;

  routing_pool_kernel<<<64, 256, 0, stream>>>(hidden, rpart);
  routing_finish_kernel<<<1, 256, 0, stream>>>(rpart, router, e_idx);
  convert_bf16_kernel<<<(BS_*D_)/2048, 256, 0, stream>>>(hidden, xbf);
  tt_prep_kernel<<<dim3(L_, 2, 16), 256, 0, stream>>>(qc[0],qc[1],qc[2],qc[3],qc[4],qc[5],
                                                      vc[0],vc[1],vc[2],vc[3],vc[4],vc[5],
                                                      Wq, Wv, e_idx, wqkv);
  convert_wk_kernel<<<(L_*D_*D_)/2048, 256, 0, stream>>>(Wk, wqkv);
  convert_bf16_kernel<<<(L_*D_*D_)/2048, 256, 0, stream>>>(Wo, wobf);

  for (int l = 0; l < L_; ++l) {
    gemm_bt<true><<<dim3(12,128), 256, 0, stream>>>(xbf, wqkv + (size_t)l*2304*D_,
        bq + l*D_, bk + l*D_, bv + l*D_, qkv, vt, 2304);
    flash_kernel<<<3072, 256, 0, stream>>>(qkv, vt, ctx);
    gemm_bt<false><<<dim3(4,128), 256, 0, stream>>>(ctx, wobf + (size_t)l*D_*D_,
        bo + l*D_, nullptr, nullptr, projb, nullptr, 768);
    if (l == 0)
      ln_kernel<true,false><<<BS_/4, 256, 0, stream>>>(hidden, xbf, projb,
          lns + l*D_, lnb + l*D_, nullptr);
    else if (l == L_-1)
      ln_kernel<false,true><<<BS_/4, 256, 0, stream>>>(nullptr, xbf, projb,
          lns + l*D_, lnb + l*D_, out);
    else
      ln_kernel<false,false><<<BS_/4, 256, 0, stream>>>(nullptr, xbf, projb,
          lns + l*D_, lnb + l*D_, nullptr);
  }
}